// Round 6
// baseline (311.771 us; speedup 1.0000x reference)
//
#include <hip/hip_runtime.h>
#include <hip/hip_bf16.h>

#define Bn 8
#define Qn 300
#define Pn 5
#define RSn 256
#define QSn 768
#define NCn 396
#define MTOT 10880
#define THRL -1.3862943611198906f   // log(0.2/0.8): sigmoid(x)>0.2 <=> x>THRL

typedef __attribute__((ext_vector_type(8))) short short8;
typedef __attribute__((ext_vector_type(4))) float float4v;

__device__ inline float wred(float v){
  #pragma unroll
  for (int off = 32; off; off >>= 1) v += __shfl_xor(v, off);
  return v;
}

__device__ __forceinline__ unsigned short f2bf(float f){
  union { float f; unsigned int u; } c; c.f = f;
  return (unsigned short)((c.u + 0x7FFF + ((c.u >> 16) & 1)) >> 16);   // RNE
}

// async global->LDS DMA, 16B per lane; LDS dest = uniform base + lane*16
__device__ __forceinline__ void gld_lds16(const short* g, short* l){
  __builtin_amdgcn_global_load_lds(
      (const __attribute__((address_space(1))) void*)g,
      (__attribute__((address_space(3))) void*)l, 16, 0, 0);
}

// =====================================================================
// D1: k_front — blocks [0,768): convW f32 -> bf16 swizzled Wswz[s][kc][lk][n][8]
//               [768,800): mask detect ; [800,840): query pooling
// =====================================================================
__global__ void k_front(const float* cw0, const float* cw1, const float* cw2, const float* cw3,
                        short* Wswz, const int* __restrict__ m0, int* det,
                        const float* __restrict__ pl, const float* __restrict__ hs,
                        float* pooled, int* flags){
  int bx = blockIdx.x;
  if (bx < 768){
    int s = bx / 192;
    int linear = (bx % 192)*256 + threadIdx.x;    // 0..49151 per scale
    int q = linear & 63, n = linear >> 6;         // k-quad q, row n
    const float* src = (s==0)?cw0:(s==1)?cw1:(s==2)?cw2:cw3;
    float4 f = *(const float4*)(src + (size_t)n*256 + q*4);
    int kc = q >> 3, lk = (q >> 1) & 3, e0 = (q & 1)*4;
    short* dst = Wswz + ((size_t)(s*8 + kc))*24576 + lk*6144 + n*8 + e0;
    short4 sv;
    sv.x = (short)f2bf(f.x); sv.y = (short)f2bf(f.y);
    sv.z = (short)f2bf(f.z); sv.w = (short)f2bf(f.w);
    *(short4*)dst = sv;
    return;
  }
  if (bx < 800){
    int i = (bx - 768) * 256 + threadIdx.x;   // 8192 ints = 32KB, safe under all layouts
    int v = m0[i];
    if (v != 0 && v != 1) atomicOr(&det[0], 1);
    if (v != 0 && v != 0x3F800000) atomicOr(&det[1], 1);
    return;
  }
  // ---- query pooling
  __shared__ float msk[Qn];
  int bb = (bx - 800) / Pn, p = (bx - 800) % Pn;
  int t = threadIdx.x;
  for (int q = t; q < Qn; q += 256)
    msk[q] = (pl[(bb*Qn + q)*Pn + p] > THRL) ? 1.f : 0.f;
  __syncthreads();
  const float* hb = hs + (size_t)bb*Qn*RSn + t;
  float ssum = 0.f, cnt = 0.f;
  for (int q = 0; q < Qn; ++q){
    float m = msk[q];
    cnt += m;
    ssum = fmaf(m, hb[(size_t)q*RSn], ssum);
  }
  pooled[(bb*Pn + p)*RSn + t] = (cnt > 0.f) ? ssum / cnt : 0.f;
  if (t == 0) flags[bb*Pn + p] = (cnt > 0.f) ? 1 : 0;
}

// gather 4-wide x 2-row window -> two pooled tokens (xs already /4/mp)
__device__ __forceinline__ void pool_win(const float* Fb, const float* Pb,
    const void* M, int mbase, int mode, int i00, int H,
    float& o0, float& im0, float& o1, float& im1){
  float4 fa = *(const float4*)(Fb + i00);
  float4 fb2 = *(const float4*)(Fb + i00 + H);
  float4 pa = *(const float4*)(Pb + i00);
  float4 pb2 = *(const float4*)(Pb + i00 + H);
  float wa[4], wbm[4];
  if (mode == 0){
    int4 ma = *(const int4*)((const int*)M + mbase + i00);
    int4 mb = *(const int4*)((const int*)M + mbase + i00 + H);
    wa[0] = ma.x ? 0.f:1.f; wa[1] = ma.y ? 0.f:1.f; wa[2] = ma.z ? 0.f:1.f; wa[3] = ma.w ? 0.f:1.f;
    wbm[0] = mb.x ? 0.f:1.f; wbm[1] = mb.y ? 0.f:1.f; wbm[2] = mb.z ? 0.f:1.f; wbm[3] = mb.w ? 0.f:1.f;
  } else if (mode == 1){
    const unsigned char* Mb = (const unsigned char*)M + mbase;
    uchar4 ma = *(const uchar4*)(Mb + i00);
    uchar4 mb = *(const uchar4*)(Mb + i00 + H);
    wa[0] = ma.x ? 0.f:1.f; wa[1] = ma.y ? 0.f:1.f; wa[2] = ma.z ? 0.f:1.f; wa[3] = ma.w ? 0.f:1.f;
    wbm[0] = mb.x ? 0.f:1.f; wbm[1] = mb.y ? 0.f:1.f; wbm[2] = mb.z ? 0.f:1.f; wbm[3] = mb.w ? 0.f:1.f;
  } else {
    float4 ma = *(const float4*)((const float*)M + mbase + i00);
    float4 mb = *(const float4*)((const float*)M + mbase + i00 + H);
    wa[0] = 1.f-ma.x; wa[1] = 1.f-ma.y; wa[2] = 1.f-ma.z; wa[3] = 1.f-ma.w;
    wbm[0] = 1.f-mb.x; wbm[1] = 1.f-mb.y; wbm[2] = 1.f-mb.z; wbm[3] = 1.f-mb.w;
  }
  float ff[4] = {fa.x+pa.x, fa.y+pa.y, fa.z+pa.z, fa.w+pa.w};
  float gg[4] = {fb2.x+pb2.x, fb2.y+pb2.y, fb2.z+pb2.z, fb2.w+pb2.w};
  {
    float xs = ff[0]*wa[0] + ff[1]*wa[1] + gg[0]*wbm[0] + gg[1]*wbm[1];
    float ms = wa[0] + wa[1] + wbm[0] + wbm[1];
    float mp = fmaxf(ms * 0.25f, 1e-6f); im0 = 1.f / mp; o0 = xs * 0.25f * im0;
  }
  {
    float xs = ff[2]*wa[2] + ff[3]*wa[3] + gg[2]*wbm[2] + gg[3]*wbm[3];
    float ms = wa[2] + wa[3] + wbm[2] + wbm[3];
    float mp = fmaxf(ms * 0.25f, 1e-6f); im1 = 1.f / mp; o1 = xs * 0.25f * im1;
  }
}

// =====================================================================
// D2: k_mid — blocks [0,8192): pool (feat+pos)*(1-mask) -> ATb[k][m] bf16 + invmp
//             blocks [8192,8240): query tokens + LN -> qt
// =====================================================================
__global__ void k_mid(const float* f0, const float* p0, const void* m0,
                      const float* f1, const float* p1, const void* m1,
                      const float* f2, const float* p2, const void* m2,
                      const float* f3, const float* p3, const void* m3,
                      const int* __restrict__ det, unsigned short* ATb, float* invmp,
                      const float* __restrict__ lq, const float* __restrict__ Wq,
                      const float* __restrict__ bq, const float* __restrict__ qng,
                      const float* __restrict__ qnb, const float* __restrict__ pooled,
                      const int* __restrict__ flags, float* qt){
  int bx = blockIdx.x;
  if (bx < 8192){
    int s = bx >> 11, b = (bx >> 8) & 7, c = bx & 255;
    const float* F; const float* Pp; const void* M; int H, SB;
    if (s == 0){ F=f0; Pp=p0; M=m0; H=64; SB=0;     }
    else if (s == 1){ F=f1; Pp=p1; M=m1; H=32; SB=8192;  }
    else if (s == 2){ F=f2; Pp=p2; M=m2; H=16; SB=10240; }
    else            { F=f3; Pp=p3; M=m3; H=8;  SB=10752; }
    int OW = H >> 1, T = OW * OW;
    int OW2 = OW >> 1, T2 = T >> 1;
    int mode = (det[0] == 0) ? 0 : ((det[1] == 0) ? 2 : 1);
    const float* Fb = F + (size_t)(b*256 + c)*H*H;
    const float* Pb = Pp + (size_t)(b*256 + c)*H*H;
    int mbase = b*H*H;
    int t = threadIdx.x;
    unsigned short* Arow = ATb + (size_t)c*MTOT;
    if (T2 == 512){
      // two token-pairs, straight-line so loads pipeline
      int tkA = t, tkB = t + 256;
      int phA = tkA / OW2, pwA = tkA - phA*OW2;
      int phB = tkB / OW2, pwB = tkB - phB*OW2;
      int iA = (phA*2)*H + pwA*4, iB = (phB*2)*H + pwB*4;
      float a0,ia0,a1,ia1, b0,ib0,b1v,ib1;
      pool_win(Fb, Pb, M, mbase, mode, iA, H, a0, ia0, a1, ia1);
      pool_win(Fb, Pb, M, mbase, mode, iB, H, b0, ib0, b1v, ib1);
      int mA = SB + b*T + tkA*2, mB = SB + b*T + tkB*2;
      *(unsigned int*)(Arow + mA) = (unsigned int)f2bf(a0) | ((unsigned int)f2bf(a1) << 16);
      *(unsigned int*)(Arow + mB) = (unsigned int)f2bf(b0) | ((unsigned int)f2bf(b1v) << 16);
      if (c == 0){ invmp[mA] = ia0; invmp[mA+1] = ia1; invmp[mB] = ib0; invmp[mB+1] = ib1; }
    } else if (t < T2){
      int ph = t / OW2, pw = t - ph*OW2;
      int i00 = (ph*2)*H + pw*4;
      float x0,i0, x1,i1;
      pool_win(Fb, Pb, M, mbase, mode, i00, H, x0, i0, x1, i1);
      int mIdx = SB + b*T + t*2;
      *(unsigned int*)(Arow + mIdx) = (unsigned int)f2bf(x0) | ((unsigned int)f2bf(x1) << 16);
      if (c == 0){ invmp[mIdx] = i0; invmp[mIdx+1] = i1; }
    }
    return;
  }
  // ---- query tokens + LN
  __shared__ float s1[4], s2[4];
  int qbx = bx - 8192;
  int b = qbx / 6, j = qbx % 6;
  int t = threadIdx.x;
  float v0 = lq[j*QSn + t], v1 = lq[j*QSn + t + 256], v2 = lq[j*QSn + t + 512];
  int any = flags[b*Pn] | flags[b*Pn+1] | flags[b*Pn+2] | flags[b*Pn+3] | flags[b*Pn+4];
  if (j > 0 && any){
    const float* pp = pooled + (b*Pn + (j-1))*RSn;
    float a0 = 0.f, a1 = 0.f, a2 = 0.f;
    for (int c = 0; c < RSn; ++c){
      float pv = pp[c];
      a0 = fmaf(pv, Wq[c*QSn + t      ], a0);
      a1 = fmaf(pv, Wq[c*QSn + t + 256], a1);
      a2 = fmaf(pv, Wq[c*QSn + t + 512], a2);
    }
    v0 += a0 + bq[t]; v1 += a1 + bq[t+256]; v2 += a2 + bq[t+512];
  }
  float sm = v0 + v1 + v2, sq = v0*v0 + v1*v1 + v2*v2;
  sm = wred(sm); sq = wred(sq);
  int wid = t >> 6, lane = t & 63;
  if (lane == 0){ s1[wid] = sm; s2[wid] = sq; }
  __syncthreads();
  float S  = s1[0] + s1[1] + s1[2] + s1[3];
  float SQ = s2[0] + s2[1] + s2[2] + s2[3];
  float mu = S * (1.f/QSn), var = SQ * (1.f/QSn) - mu*mu;
  float rs = rsqrtf(var + 1e-5f);
  float* o = qt + (b*6 + j)*QSn;
  o[t      ] = (v0 - mu)*rs*qng[t      ] + qnb[t      ];
  o[t + 256] = (v1 - mu)*rs*qng[t + 256] + qnb[t + 256];
  o[t + 512] = (v2 - mu)*rs*qng[t + 512] + qnb[t + 512];
}

// =====================================================================
// D3: fused MFMA GEMM + bias + LayerNorm + token-sum.  680 blocks x 256 thr.
// Block tile: 16 m x 768 n, K=256 in 8 chunks of 32.
// B staged per-kc via global_load_lds DMA (identity copy of pre-swizzled Wswz);
// A-tile LDS-transposed from ATb[k][m]. LDS total ~57 KB -> 2 blocks/CU.
// =====================================================================
__global__ __launch_bounds__(256, 2) void k_gemm_ln(
    const unsigned short* __restrict__ ATb, const short* __restrict__ Wswz,
    const float* __restrict__ invmp,
    const float* cb0, const float* cb1, const float* cb2, const float* cb3,
    const float* lg0, const float* lb0, const float* lg1, const float* lb1,
    const float* lg2, const float* lb2, const float* lg3, const float* lb3,
    float* __restrict__ ctxsum){
  __shared__ short Bsh[24576];        // [lk][n][8e] : 48 KB
  __shared__ short As[16*264];        // [m][k] rows padded to 264
  __shared__ float lsum[4][16], lsq[4][16];
  int m0 = blockIdx.x * 16;
  int s, b;
  if (m0 < 8192){ s=0; b=m0>>10; }
  else if (m0 < 10240){ s=1; b=(m0-8192)>>8; }
  else if (m0 < 10752){ s=2; b=(m0-10240)>>6; }
  else { s=3; b=(m0-10752)>>4; }
  const float *CB, *LG, *LB;
  if (s==0){ CB=cb0; LG=lg0; LB=lb0; }
  else if (s==1){ CB=cb1; LG=lg1; LB=lb1; }
  else if (s==2){ CB=cb2; LG=lg2; LB=lb2; }
  else { CB=cb3; LG=lg3; LB=lb3; }

  int t = threadIdx.x;
  int wid = t >> 6, l = t & 63;
  int lm = l & 15, lk = l >> 4;
  int nfb = wid * 12;                 // wave's 12 frags -> n in [nfb*16, nfb*16+192)

  // ---- A-tile transpose: thread t owns channel k=t, 16 m-values (32 B)
  {
    const unsigned short* src = ATb + (size_t)t*MTOT + m0;
    short8 a0 = *(const short8*)(src);
    short8 a1 = *(const short8*)(src + 8);
    #pragma unroll
    for (int e = 0; e < 8; ++e){
      As[e*264 + t]     = a0[e];
      As[(e+8)*264 + t] = a1[e];
    }
  }

  float4v acc[12];
  #pragma unroll
  for (int nf = 0; nf < 12; ++nf) acc[nf] = (float4v){0.f,0.f,0.f,0.f};

  #pragma unroll 1
  for (int kc = 0; kc < 8; ++kc){
    const short* slice = Wswz + ((size_t)(s*8 + kc))*24576;
    #pragma unroll
    for (int j = 0; j < 12; ++j){
      int chunk = wid*12 + j;
      gld_lds16(slice + chunk*512 + l*8, Bsh + chunk*512);
    }
    __syncthreads();                 // drain DMA (+ A-tile writes on kc==0)
    short8 a = *(const short8*)(As + lm*264 + kc*32 + lk*8);
    const short* bb = Bsh + lk*6144 + lm*8;
    #pragma unroll
    for (int nf = 0; nf < 12; ++nf){
      short8 bf = *(const short8*)(bb + (size_t)(nfb+nf)*128);
      acc[nf] = __builtin_amdgcn_mfma_f32_16x16x32_bf16(a, bf, acc[nf], 0, 0, 0);
    }
    __syncthreads();                 // all reads done before next DMA overwrites
  }

  // ---- epilogue: P = acc + CB[n]*invmp[m]; per-row LN; token-sum -> ctxsum[b]
  float im[4];
  #pragma unroll
  for (int r = 0; r < 4; ++r) im[r] = invmp[m0 + lk*4 + r];

  float sum[4] = {0,0,0,0}, sq[4] = {0,0,0,0};
  #pragma unroll
  for (int nf = 0; nf < 12; ++nf){
    float cbv = CB[(nfb+nf)*16 + lm];
    #pragma unroll
    for (int r = 0; r < 4; ++r){
      float p = acc[nf][r] + cbv*im[r];
      acc[nf][r] = p;
      sum[r] += p;
      sq[r] = fmaf(p, p, sq[r]);
    }
  }
  #pragma unroll
  for (int r = 0; r < 4; ++r){
    #pragma unroll
    for (int off = 1; off < 16; off <<= 1){
      sum[r] += __shfl_xor(sum[r], off);
      sq[r]  += __shfl_xor(sq[r],  off);
    }
  }
  if (lm == 0){
    #pragma unroll
    for (int r = 0; r < 4; ++r){ lsum[wid][lk*4+r] = sum[r]; lsq[wid][lk*4+r] = sq[r]; }
  }
  __syncthreads();
  float mu[4], rs[4];
  #pragma unroll
  for (int r = 0; r < 4; ++r){
    int row = lk*4 + r;
    float S  = lsum[0][row] + lsum[1][row] + lsum[2][row] + lsum[3][row];
    float SQ = lsq[0][row]  + lsq[1][row]  + lsq[2][row]  + lsq[3][row];
    mu[r] = S * (1.f/768.f);
    float var = SQ * (1.f/768.f) - mu[r]*mu[r];
    rs[r] = rsqrtf(var + 1e-5f);
  }
  #pragma unroll
  for (int nf = 0; nf < 12; ++nf){
    int n = (nfb+nf)*16 + lm;
    float g = LG[n], bb2 = LB[n];
    float tv = 0.f;
    #pragma unroll
    for (int r = 0; r < 4; ++r) tv += (acc[nf][r] - mu[r]) * rs[r];
    tv = tv*g + 4.f*bb2;              // 4 rows of this lane-group
    tv += __shfl_xor(tv, 16);
    tv += __shfl_xor(tv, 32);         // sum over all 16 rows
    if (lk == 0) atomicAdd(&ctxsum[b*768 + n], tv);
  }
}

// =====================================================================
// D4: k_hpre — hpre = v @ W1 + b1 ; v rebuilt from qt+ctxsum in LDS.
// Grid 24 x 256. Block: 32 cols; thread (ow, half, kq): 4 batches, 192 c.
// LDS-reduce across kq -> plain store (no atomics, no pre-zero).
// =====================================================================
__global__ void k_hpre(const float* __restrict__ qt, const float* __restrict__ ctxsum,
                       const float* __restrict__ W1, const float* __restrict__ b1,
                       float* __restrict__ hpre){
  __shared__ float vsh[Bn][768];
  __shared__ float part[4][Bn][32];
  int n0 = blockIdx.x * 32;
  int t = threadIdx.x;
  for (int i = t; i < Bn*768; i += 256){
    int b = i / 768, c = i - b*768;
    const float* q = qt + (size_t)b*6*768;
    float pm = q[768+c] + q[2*768+c] + q[3*768+c] + q[4*768+c] + q[5*768+c];
    vsh[b][c] = q[c] + 0.2f*pm + ctxsum[b*768 + c]*(1.f/680.f);
  }
  __syncthreads();
  int ow = t & 31, half = (t >> 5) & 1, kq = t >> 6;
  int o = n0 + ow, c0 = kq*192;
  float acc[4] = {0,0,0,0};
  const float* w = W1 + (size_t)c0*768 + o;
  #pragma unroll 4
  for (int cl = 0; cl < 192; ++cl){
    float wv = w[(size_t)cl*768];
    #pragma unroll
    for (int bi = 0; bi < 4; ++bi)
      acc[bi] = fmaf(vsh[half*4+bi][c0+cl], wv, acc[bi]);
  }
  #pragma unroll
  for (int bi = 0; bi < 4; ++bi) part[kq][half*4+bi][ow] = acc[bi];
  __syncthreads();
  int b = t >> 5, oo = t & 31;       // 256 = 8 b x 32 cols
  float v = part[0][b][oo] + part[1][b][oo] + part[2][b][oo] + part[3][b][oo] + b1[n0+oo];
  hpre[b*768 + n0 + oo] = v;
}

// =====================================================================
// D5: k_out — out = relu(hpre) @ W2 + b2. Grid 13 x 256 (32 cols/block).
// =====================================================================
__global__ void k_out(const float* __restrict__ hpre, const float* __restrict__ W2,
                      const float* __restrict__ b2, float* __restrict__ out){
  __shared__ float hsh[Bn][768];
  __shared__ float part[4][Bn][32];
  int n0 = blockIdx.x * 32;
  int t = threadIdx.x;
  for (int i = t; i < Bn*768; i += 256)
    hsh[0][i] = fmaxf(hpre[i], 0.f);
  __syncthreads();
  int ow = t & 31, half = (t >> 5) & 1, kq = t >> 6;
  int o = n0 + ow, c0 = kq*192;
  bool valid = (o < NCn);
  float acc[4] = {0,0,0,0};
  const float* w = W2 + (size_t)c0*NCn + o;
  if (valid){
    #pragma unroll 4
    for (int cl = 0; cl < 192; ++cl){
      float wv = w[(size_t)cl*NCn];
      #pragma unroll
      for (int bi = 0; bi < 4; ++bi)
        acc[bi] = fmaf(hsh[half*4+bi][c0+cl], wv, acc[bi]);
    }
  }
  #pragma unroll
  for (int bi = 0; bi < 4; ++bi) part[kq][half*4+bi][ow] = acc[bi];
  __syncthreads();
  int b = t >> 5, oo = t & 31;
  int oc = n0 + oo;
  if (oc < NCn){
    float v = part[0][b][oo] + part[1][b][oo] + part[2][b][oo] + part[3][b][oo] + b2[oc];
    out[b*NCn + oc] = v;
  }
}

extern "C" void kernel_launch(void* const* d_in, const int* in_sizes, int n_in,
                              void* d_out, int out_size, void* d_ws, size_t ws_size,
                              hipStream_t stream){
  const float* pl = (const float*)d_in[0];
  const float* hs = (const float*)d_in[2];
  const float* feat[4]; const float* pos[4]; const void* mask[4];
  const float* cw[4]; const float* cb[4]; const float* lg[4]; const float* lb[4];
  for (int s = 0; s < 4; ++s){
    int base = 3 + 7*s;
    feat[s] = (const float*)d_in[base];
    pos[s]  = (const float*)d_in[base+1];
    mask[s] = d_in[base+2];
    cw[s]   = (const float*)d_in[base+3];
    cb[s]   = (const float*)d_in[base+4];
    lg[s]   = (const float*)d_in[base+5];
    lb[s]   = (const float*)d_in[base+6];
  }
  const float* lq  = (const float*)d_in[31];
  const float* Wq  = (const float*)d_in[32];
  const float* bq  = (const float*)d_in[33];
  const float* qng = (const float*)d_in[34];
  const float* qnb = (const float*)d_in[35];
  const float* W1  = (const float*)d_in[36];
  const float* b1  = (const float*)d_in[37];
  const float* W2  = (const float*)d_in[38];
  const float* b2  = (const float*)d_in[39];
  float* out = (float*)d_out;

  // ---- workspace layout (~7.5 MB)
  unsigned short* ATb = (unsigned short*)d_ws;         // [256][10880] bf16
  short* Wswz   = (short*)(ATb + (size_t)256*MTOT);    // [4][8][4][768][8] bf16 = 1.5 MB
  float* invmp  = (float*)(Wswz + (size_t)4*8*4*768*8);// 10880
  float* pooled = invmp + MTOT;                        // 40*256
  float* qt     = pooled + 40*RSn;                     // 8*6*768
  // zeroed: ctxsum | det
  float* ctxsum = qt + Bn*6*QSn;                       // 8*768
  int*   det    = (int*)(ctxsum + Bn*QSn);             // 4 ints
  int*   flags  = det + 4;                             // 40 ints
  float* hpre   = (float*)(flags + 40);                // 8*768

  size_t zbytes = (size_t)(Bn*QSn)*sizeof(float) + 4*sizeof(int);
  hipMemsetAsync(ctxsum, 0, zbytes, stream);
  k_front<<<840, 256, 0, stream>>>(cw[0], cw[1], cw[2], cw[3], Wswz,
                                   (const int*)mask[0], det, pl, hs, pooled, flags);
  k_mid<<<8240, 256, 0, stream>>>(feat[0], pos[0], mask[0],
                                  feat[1], pos[1], mask[1],
                                  feat[2], pos[2], mask[2],
                                  feat[3], pos[3], mask[3],
                                  det, ATb, invmp,
                                  lq, Wq, bq, qng, qnb, pooled, flags, qt);
  k_gemm_ln<<<680, 256, 0, stream>>>(ATb, Wswz, invmp,
                                     cb[0], cb[1], cb[2], cb[3],
                                     lg[0], lb[0], lg[1], lb[1],
                                     lg[2], lb[2], lg[3], lb[3], ctxsum);
  k_hpre<<<24, 256, 0, stream>>>(qt, ctxsum, W1, b1, hpre);
  k_out<<<13, 256, 0, stream>>>(hpre, W2, b2, out);
}

// Round 7
// 292.365 us; speedup vs baseline: 1.0664x; 1.0664x over previous
//
#include <hip/hip_runtime.h>
#include <hip/hip_bf16.h>

#define Bn 8
#define Qn 300
#define Pn 5
#define RSn 256
#define QSn 768
#define NCn 396
#define MTOT 10880
#define THRL -1.3862943611198906f   // log(0.2/0.8): sigmoid(x)>0.2 <=> x>THRL

typedef __attribute__((ext_vector_type(8))) short short8;
typedef __attribute__((ext_vector_type(4))) float float4v;

__device__ inline float wred(float v){
  #pragma unroll
  for (int off = 32; off; off >>= 1) v += __shfl_xor(v, off);
  return v;
}

__device__ __forceinline__ unsigned short f2bf(float f){
  union { float f; unsigned int u; } c; c.f = f;
  return (unsigned short)((c.u + 0x7FFF + ((c.u >> 16) & 1)) >> 16);   // RNE
}

// async global->LDS DMA, 16B per lane; LDS dest = uniform base + lane*16
__device__ __forceinline__ void gld_lds16(const short* g, short* l){
  __builtin_amdgcn_global_load_lds(
      (const __attribute__((address_space(1))) void*)g,
      (__attribute__((address_space(3))) void*)l, 16, 0, 0);
}

// =====================================================================
// D1: k_front — [0,768): convW f32 -> bf16 swizzled Wswz[s][kc][lk][n][8]
//               768: mask detect (ballot, no pre-zero) ; [769,809): query pooling ;
//               [809,815): zero ctxsum
// =====================================================================
__global__ void k_front(const float* cw0, const float* cw1, const float* cw2, const float* cw3,
                        short* Wswz, const int* __restrict__ m0, int* det,
                        const float* __restrict__ pl, const float* __restrict__ hs,
                        float* pooled, int* flags, float* ctxsum){
  int bx = blockIdx.x;
  int t = threadIdx.x;
  if (bx < 768){
    int s = bx / 192;
    int linear = (bx % 192)*256 + t;              // 0..49151 per scale
    int q = linear & 63, n = linear >> 6;         // k-quad q, row n
    const float* src = (s==0)?cw0:(s==1)?cw1:(s==2)?cw2:cw3;
    float4 f = *(const float4*)(src + (size_t)n*256 + q*4);
    int kc = q >> 3, lk = (q >> 1) & 3, e0 = (q & 1)*4;
    short* dst = Wswz + ((size_t)(s*8 + kc))*24576 + lk*6144 + n*8 + e0;
    short4 sv;
    sv.x = (short)f2bf(f.x); sv.y = (short)f2bf(f.y);
    sv.z = (short)f2bf(f.z); sv.w = (short)f2bf(f.w);
    *(short4*)dst = sv;
    return;
  }
  if (bx == 768){
    // detect mask storage over first 8192 ints (32KB, safe under all layouts)
    __shared__ int r0[4], r1[4];
    const int* mm = m0 + t*32;
    int d0 = 0, d1 = 0;
    #pragma unroll 8
    for (int i = 0; i < 32; ++i){
      int v = mm[i];
      d0 |= (v != 0 && v != 1);
      d1 |= (v != 0 && v != 0x3F800000);
    }
    unsigned long long bal0 = __ballot(d0), bal1 = __ballot(d1);
    int wid = t >> 6;
    if ((t & 63) == 0){ r0[wid] = (bal0 != 0ull); r1[wid] = (bal1 != 0ull); }
    __syncthreads();
    if (t == 0){
      det[0] = r0[0] | r0[1] | r0[2] | r0[3];
      det[1] = r1[0] | r1[1] | r1[2] | r1[3];
    }
    return;
  }
  if (bx >= 809){
    // zero ctxsum (8*768 floats) : 6 blocks x 256 thr x float4
    int idx = ((bx - 809)*256 + t)*4;
    *(float4*)(ctxsum + idx) = (float4){0.f,0.f,0.f,0.f};
    return;
  }
  // ---- query pooling
  __shared__ float msk[Qn];
  int bb = (bx - 769) / Pn, p = (bx - 769) % Pn;
  for (int q = t; q < Qn; q += 256)
    msk[q] = (pl[(bb*Qn + q)*Pn + p] > THRL) ? 1.f : 0.f;
  __syncthreads();
  const float* hb = hs + (size_t)bb*Qn*RSn + t;
  float ssum = 0.f, cnt = 0.f;
  for (int q = 0; q < Qn; ++q){
    float m = msk[q];
    cnt += m;
    ssum = fmaf(m, hb[(size_t)q*RSn], ssum);
  }
  pooled[(bb*Pn + p)*RSn + t] = (cnt > 0.f) ? ssum / cnt : 0.f;
  if (t == 0) flags[bb*Pn + p] = (cnt > 0.f) ? 1 : 0;
}

// =====================================================================
// D2: k_mid — blocks [0,48): query tokens + LN -> qt  (FIRST so they overlap)
//             blocks [48,2096): pool (feat+pos)*(1-mask) -> ATb[k][m] + invmp,
//                               4 channels per block, mask decoded once/token
// =====================================================================
__global__ void k_mid(const float* f0, const float* p0, const void* m0,
                      const float* f1, const float* p1, const void* m1,
                      const float* f2, const float* p2, const void* m2,
                      const float* f3, const float* p3, const void* m3,
                      const int* __restrict__ det, unsigned short* ATb, float* invmp,
                      const float* __restrict__ lq, const float* __restrict__ Wq,
                      const float* __restrict__ bq, const float* __restrict__ qng,
                      const float* __restrict__ qnb, const float* __restrict__ pooled,
                      const int* __restrict__ flags, float* qt){
  __shared__ float pq[256];
  __shared__ float s1[4], s2[4];
  int bx = blockIdx.x;
  int t = threadIdx.x;
  if (bx >= 48){
    int p = bx - 48;
    int s = p >> 9, b = (p >> 6) & 7, c0 = (p & 63) << 2;
    const float* F; const float* Pp; const void* M; int H, SB;
    if (s == 0){ F=f0; Pp=p0; M=m0; H=64; SB=0;     }
    else if (s == 1){ F=f1; Pp=p1; M=m1; H=32; SB=8192;  }
    else if (s == 2){ F=f2; Pp=p2; M=m2; H=16; SB=10240; }
    else            { F=f3; Pp=p3; M=m3; H=8;  SB=10752; }
    int OW = H >> 1, T = OW * OW;
    int OW2 = OW >> 1, T2 = T >> 1;
    int HH = H*H;
    int mode = (det[0] == 0) ? 0 : ((det[1] == 0) ? 2 : 1);
    size_t plane = (size_t)(b*256 + c0)*HH;
    const float* Fb = F + plane;
    const float* Pb = Pp + plane;
    int mbase = b*HH;
    for (int tk = t; tk < T2; tk += 256){
      int ph = tk / OW2, pw = tk - ph*OW2;
      int i00 = (ph*2)*H + pw*4;
      // ---- mask weights, once per token-pair
      float w[8];
      if (mode == 0){
        int4 ma = *(const int4*)((const int*)M + mbase + i00);
        int4 mb = *(const int4*)((const int*)M + mbase + i00 + H);
        w[0]=ma.x?0.f:1.f; w[1]=ma.y?0.f:1.f; w[2]=ma.z?0.f:1.f; w[3]=ma.w?0.f:1.f;
        w[4]=mb.x?0.f:1.f; w[5]=mb.y?0.f:1.f; w[6]=mb.z?0.f:1.f; w[7]=mb.w?0.f:1.f;
      } else if (mode == 1){
        const unsigned char* Mb = (const unsigned char*)M + mbase;
        uchar4 ma = *(const uchar4*)(Mb + i00);
        uchar4 mb = *(const uchar4*)(Mb + i00 + H);
        w[0]=ma.x?0.f:1.f; w[1]=ma.y?0.f:1.f; w[2]=ma.z?0.f:1.f; w[3]=ma.w?0.f:1.f;
        w[4]=mb.x?0.f:1.f; w[5]=mb.y?0.f:1.f; w[6]=mb.z?0.f:1.f; w[7]=mb.w?0.f:1.f;
      } else {
        float4 ma = *(const float4*)((const float*)M + mbase + i00);
        float4 mb = *(const float4*)((const float*)M + mbase + i00 + H);
        w[0]=1.f-ma.x; w[1]=1.f-ma.y; w[2]=1.f-ma.z; w[3]=1.f-ma.w;
        w[4]=1.f-mb.x; w[5]=1.f-mb.y; w[6]=1.f-mb.z; w[7]=1.f-mb.w;
      }
      float ms0 = w[0]+w[1]+w[4]+w[5];
      float ms1 = w[2]+w[3]+w[6]+w[7];
      float im0 = 1.f / fmaxf(ms0*0.25f, 1e-6f);
      float im1 = 1.f / fmaxf(ms1*0.25f, 1e-6f);
      float sc0 = 0.25f*im0, sc1 = 0.25f*im1;
      int mIdx = SB + b*T + tk*2;
      // ---- 4 channels, weights reused
      #pragma unroll
      for (int cc = 0; cc < 4; ++cc){
        const float* Fc = Fb + cc*HH;
        const float* Pc = Pb + cc*HH;
        float4 fa  = *(const float4*)(Fc + i00);
        float4 fb2 = *(const float4*)(Fc + i00 + H);
        float4 pa  = *(const float4*)(Pc + i00);
        float4 pb2 = *(const float4*)(Pc + i00 + H);
        float x0 = (fa.x+pa.x)*w[0] + (fa.y+pa.y)*w[1] + (fb2.x+pb2.x)*w[4] + (fb2.y+pb2.y)*w[5];
        float x1 = (fa.z+pa.z)*w[2] + (fa.w+pa.w)*w[3] + (fb2.z+pb2.z)*w[6] + (fb2.w+pb2.w)*w[7];
        *(unsigned int*)(ATb + (size_t)(c0+cc)*MTOT + mIdx) =
            (unsigned int)f2bf(x0*sc0) | ((unsigned int)f2bf(x1*sc1) << 16);
      }
      if (c0 == 0){ invmp[mIdx] = im0; invmp[mIdx+1] = im1; }
    }
    return;
  }
  // ---- query tokens + LN (blocks 0..47, overlap with pooling)
  int b = bx / 6, j = bx % 6;
  float v0 = lq[j*QSn + t], v1 = lq[j*QSn + t + 256], v2 = lq[j*QSn + t + 512];
  int any = flags[b*Pn] | flags[b*Pn+1] | flags[b*Pn+2] | flags[b*Pn+3] | flags[b*Pn+4];
  if (j > 0 && any){
    pq[t] = pooled[(b*Pn + (j-1))*RSn + t];
    __syncthreads();
    float a0 = 0.f, a1 = 0.f, a2 = 0.f;
    #pragma unroll 8
    for (int c = 0; c < RSn; ++c){
      float pv = pq[c];
      a0 = fmaf(pv, Wq[c*QSn + t      ], a0);
      a1 = fmaf(pv, Wq[c*QSn + t + 256], a1);
      a2 = fmaf(pv, Wq[c*QSn + t + 512], a2);
    }
    v0 += a0 + bq[t]; v1 += a1 + bq[t+256]; v2 += a2 + bq[t+512];
  }
  float sm = v0 + v1 + v2, sq = v0*v0 + v1*v1 + v2*v2;
  sm = wred(sm); sq = wred(sq);
  int wid = t >> 6, lane = t & 63;
  if (lane == 0){ s1[wid] = sm; s2[wid] = sq; }
  __syncthreads();
  float S  = s1[0] + s1[1] + s1[2] + s1[3];
  float SQ = s2[0] + s2[1] + s2[2] + s2[3];
  float mu = S * (1.f/QSn), var = SQ * (1.f/QSn) - mu*mu;
  float rs = rsqrtf(var + 1e-5f);
  float* o = qt + (b*6 + j)*QSn;
  o[t      ] = (v0 - mu)*rs*qng[t      ] + qnb[t      ];
  o[t + 256] = (v1 - mu)*rs*qng[t + 256] + qnb[t + 256];
  o[t + 512] = (v2 - mu)*rs*qng[t + 512] + qnb[t + 512];
}

// =====================================================================
// D3: fused MFMA GEMM + bias + LayerNorm + token-sum.  340 blocks x 256 thr.
// Block tile: 32 m x 768 n, K=256 in 8 chunks of 32.
// A transposed via Bsh scratch -> registers (aReg[2][8]); K-loop LDS is B-only
// (48 KB DMA per kc via global_load_lds). All 340 blocks co-resident (2/CU).
// =====================================================================
__global__ __launch_bounds__(256, 2) void k_gemm_ln(
    const unsigned short* __restrict__ ATb, const short* __restrict__ Wswz,
    const float* __restrict__ invmp,
    const float* cb0, const float* cb1, const float* cb2, const float* cb3,
    const float* lg0, const float* lb0, const float* lg1, const float* lb1,
    const float* lg2, const float* lb2, const float* lg3, const float* lb3,
    float* __restrict__ ctxsum){
  __shared__ short Bsh[24576];        // 48 KB; phase-0 scratch for A-transpose
  __shared__ float lsum[4][32], lsq[4][32];
  int m0 = blockIdx.x * 32;
  int s;
  if (m0 < 8192) s = 0;
  else if (m0 < 10240) s = 1;
  else if (m0 < 10752) s = 2;
  else s = 3;
  int b0, b1;
  if (s == 0){ b0 = m0 >> 10; b1 = b0; }
  else if (s == 1){ b0 = (m0 - 8192) >> 8; b1 = b0; }
  else if (s == 2){ b0 = (m0 - 10240) >> 6; b1 = b0; }
  else { b0 = (m0 - 10752) >> 4; b1 = b0 + 1; }        // s=3: 16 rows/batch
  const float *CB, *LG, *LB;
  if (s==0){ CB=cb0; LG=lg0; LB=lb0; }
  else if (s==1){ CB=cb1; LG=lg1; LB=lb1; }
  else if (s==2){ CB=cb2; LG=lg2; LB=lb2; }
  else { CB=cb3; LG=lg3; LB=lb3; }

  int t = threadIdx.x;
  int wid = t >> 6, l = t & 63;
  int lm = l & 15, lk = l >> 4;
  int nfb = wid * 12;

  // ---- phase 0: A-tile transpose through Bsh scratch (pitch 264)
  {
    const unsigned short* src = ATb + (size_t)t*MTOT + m0;
    short8 a0 = *(const short8*)(src);
    short8 a1 = *(const short8*)(src + 8);
    short8 a2 = *(const short8*)(src + 16);
    short8 a3 = *(const short8*)(src + 24);
    #pragma unroll
    for (int e = 0; e < 8; ++e){
      Bsh[e*264 + t]      = a0[e];
      Bsh[(e+8)*264 + t]  = a1[e];
      Bsh[(e+16)*264 + t] = a2[e];
      Bsh[(e+24)*264 + t] = a3[e];
    }
  }
  __syncthreads();
  short8 aReg[2][8];
  #pragma unroll
  for (int mt = 0; mt < 2; ++mt)
    #pragma unroll
    for (int kc = 0; kc < 8; ++kc)
      aReg[mt][kc] = *(const short8*)(Bsh + (mt*16 + lm)*264 + kc*32 + lk*8);
  __syncthreads();                    // scratch reads done before DMA overwrites

  float4v acc[2][12];
  #pragma unroll
  for (int mt = 0; mt < 2; ++mt)
    #pragma unroll
    for (int nf = 0; nf < 12; ++nf) acc[mt][nf] = (float4v){0.f,0.f,0.f,0.f};

  #pragma unroll
  for (int kc = 0; kc < 8; ++kc){
    const short* slice = Wswz + ((size_t)(s*8 + kc))*24576;
    #pragma unroll
    for (int j = 0; j < 12; ++j){
      int chunk = wid*12 + j;
      gld_lds16(slice + chunk*512 + l*8, Bsh + chunk*512);
    }
    __syncthreads();                 // drain DMA
    const short* bb = Bsh + lk*6144 + lm*8;
    #pragma unroll
    for (int nf = 0; nf < 12; ++nf){
      short8 bf = *(const short8*)(bb + (size_t)(nfb+nf)*128);
      acc[0][nf] = __builtin_amdgcn_mfma_f32_16x16x32_bf16(aReg[0][kc], bf, acc[0][nf], 0, 0, 0);
      acc[1][nf] = __builtin_amdgcn_mfma_f32_16x16x32_bf16(aReg[1][kc], bf, acc[1][nf], 0, 0, 0);
    }
    __syncthreads();                 // reads done before next DMA
  }

  // ---- epilogue: bias, per-row LN stats, token-sum -> ctxsum
  float im[2][4];
  #pragma unroll
  for (int mt = 0; mt < 2; ++mt)
    #pragma unroll
    for (int r = 0; r < 4; ++r) im[mt][r] = invmp[m0 + mt*16 + lk*4 + r];

  float sum[2][4] = {{0,0,0,0},{0,0,0,0}}, sq[2][4] = {{0,0,0,0},{0,0,0,0}};
  #pragma unroll
  for (int nf = 0; nf < 12; ++nf){
    float cbv = CB[(nfb+nf)*16 + lm];
    #pragma unroll
    for (int mt = 0; mt < 2; ++mt)
      #pragma unroll
      for (int r = 0; r < 4; ++r){
        float p = acc[mt][nf][r] + cbv*im[mt][r];
        acc[mt][nf][r] = p;
        sum[mt][r] += p;
        sq[mt][r] = fmaf(p, p, sq[mt][r]);
      }
  }
  #pragma unroll
  for (int mt = 0; mt < 2; ++mt)
    #pragma unroll
    for (int r = 0; r < 4; ++r){
      #pragma unroll
      for (int off = 1; off < 16; off <<= 1){
        sum[mt][r] += __shfl_xor(sum[mt][r], off);
        sq[mt][r]  += __shfl_xor(sq[mt][r],  off);
      }
    }
  if (lm == 0){
    #pragma unroll
    for (int mt = 0; mt < 2; ++mt)
      #pragma unroll
      for (int r = 0; r < 4; ++r){
        lsum[wid][mt*16 + lk*4 + r] = sum[mt][r];
        lsq[wid][mt*16 + lk*4 + r]  = sq[mt][r];
      }
  }
  __syncthreads();
  float mu[2][4], rs[2][4];
  #pragma unroll
  for (int mt = 0; mt < 2; ++mt)
    #pragma unroll
    for (int r = 0; r < 4; ++r){
      int row = mt*16 + lk*4 + r;
      float S  = lsum[0][row] + lsum[1][row] + lsum[2][row] + lsum[3][row];
      float SQ = lsq[0][row]  + lsq[1][row]  + lsq[2][row]  + lsq[3][row];
      mu[mt][r] = S * (1.f/768.f);
      float var = SQ * (1.f/768.f) - mu[mt][r]*mu[mt][r];
      rs[mt][r] = rsqrtf(var + 1e-5f);
    }
  #pragma unroll
  for (int nf = 0; nf < 12; ++nf){
    int n = (nfb+nf)*16 + lm;
    float g = LG[n], bb2 = LB[n];
    float tv0 = 0.f, tv1 = 0.f;
    #pragma unroll
    for (int r = 0; r < 4; ++r){
      tv0 += (acc[0][nf][r] - mu[0][r]) * rs[0][r];
      tv1 += (acc[1][nf][r] - mu[1][r]) * rs[1][r];
    }
    tv0 = tv0*g + 4.f*bb2;
    tv1 = tv1*g + 4.f*bb2;
    tv0 += __shfl_xor(tv0, 16); tv0 += __shfl_xor(tv0, 32);
    tv1 += __shfl_xor(tv1, 16); tv1 += __shfl_xor(tv1, 32);
    if (lk == 0){
      atomicAdd(&ctxsum[b0*768 + n], tv0);
      atomicAdd(&ctxsum[b1*768 + n], tv1);
    }
  }
}

// =====================================================================
// D4: k_hpre — hpre = v @ W1 + b1 ; v rebuilt from qt+ctxsum in LDS.
// =====================================================================
__global__ void k_hpre(const float* __restrict__ qt, const float* __restrict__ ctxsum,
                       const float* __restrict__ W1, const float* __restrict__ b1,
                       float* __restrict__ hpre){
  __shared__ float vsh[Bn][768];
  __shared__ float part[4][Bn][32];
  int n0 = blockIdx.x * 32;
  int t = threadIdx.x;
  for (int i = t; i < Bn*768; i += 256){
    int b = i / 768, c = i - b*768;
    const float* q = qt + (size_t)b*6*768;
    float pm = q[768+c] + q[2*768+c] + q[3*768+c] + q[4*768+c] + q[5*768+c];
    vsh[b][c] = q[c] + 0.2f*pm + ctxsum[b*768 + c]*(1.f/680.f);
  }
  __syncthreads();
  int ow = t & 31, half = (t >> 5) & 1, kq = t >> 6;
  int o = n0 + ow, c0 = kq*192;
  float acc[4] = {0,0,0,0};
  const float* w = W1 + (size_t)c0*768 + o;
  #pragma unroll 4
  for (int cl = 0; cl < 192; ++cl){
    float wv = w[(size_t)cl*768];
    #pragma unroll
    for (int bi = 0; bi < 4; ++bi)
      acc[bi] = fmaf(vsh[half*4+bi][c0+cl], wv, acc[bi]);
  }
  #pragma unroll
  for (int bi = 0; bi < 4; ++bi) part[kq][half*4+bi][ow] = acc[bi];
  __syncthreads();
  int b = t >> 5, oo = t & 31;
  float v = part[0][b][oo] + part[1][b][oo] + part[2][b][oo] + part[3][b][oo] + b1[n0+oo];
  hpre[b*768 + n0 + oo] = v;
}

// =====================================================================
// D5: k_out — out = relu(hpre) @ W2 + b2.
// =====================================================================
__global__ void k_out(const float* __restrict__ hpre, const float* __restrict__ W2,
                      const float* __restrict__ b2, float* __restrict__ out){
  __shared__ float hsh[Bn][768];
  __shared__ float part[4][Bn][32];
  int n0 = blockIdx.x * 32;
  int t = threadIdx.x;
  for (int i = t; i < Bn*768; i += 256)
    hsh[0][i] = fmaxf(hpre[i], 0.f);
  __syncthreads();
  int ow = t & 31, half = (t >> 5) & 1, kq = t >> 6;
  int o = n0 + ow, c0 = kq*192;
  float acc[4] = {0,0,0,0};
  if (o < NCn){
    const float* w = W2 + (size_t)c0*NCn + o;
    #pragma unroll 4
    for (int cl = 0; cl < 192; ++cl){
      float wv = w[(size_t)cl*NCn];
      #pragma unroll
      for (int bi = 0; bi < 4; ++bi)
        acc[bi] = fmaf(hsh[half*4+bi][c0+cl], wv, acc[bi]);
    }
  }
  #pragma unroll
  for (int bi = 0; bi < 4; ++bi) part[kq][half*4+bi][ow] = acc[bi];
  __syncthreads();
  int b = t >> 5, oo = t & 31;
  int oc = n0 + oo;
  if (oc < NCn){
    float v = part[0][b][oo] + part[1][b][oo] + part[2][b][oo] + part[3][b][oo] + b2[oc];
    out[b*NCn + oc] = v;
  }
}

extern "C" void kernel_launch(void* const* d_in, const int* in_sizes, int n_in,
                              void* d_out, int out_size, void* d_ws, size_t ws_size,
                              hipStream_t stream){
  const float* pl = (const float*)d_in[0];
  const float* hs = (const float*)d_in[2];
  const float* feat[4]; const float* pos[4]; const void* mask[4];
  const float* cw[4]; const float* cb[4]; const float* lg[4]; const float* lb[4];
  for (int s = 0; s < 4; ++s){
    int base = 3 + 7*s;
    feat[s] = (const float*)d_in[base];
    pos[s]  = (const float*)d_in[base+1];
    mask[s] = d_in[base+2];
    cw[s]   = (const float*)d_in[base+3];
    cb[s]   = (const float*)d_in[base+4];
    lg[s]   = (const float*)d_in[base+5];
    lb[s]   = (const float*)d_in[base+6];
  }
  const float* lq  = (const float*)d_in[31];
  const float* Wq  = (const float*)d_in[32];
  const float* bq  = (const float*)d_in[33];
  const float* qng = (const float*)d_in[34];
  const float* qnb = (const float*)d_in[35];
  const float* W1  = (const float*)d_in[36];
  const float* b1  = (const float*)d_in[37];
  const float* W2  = (const float*)d_in[38];
  const float* b2  = (const float*)d_in[39];
  float* out = (float*)d_out;

  // ---- workspace layout (~7.5 MB)
  unsigned short* ATb = (unsigned short*)d_ws;         // [256][10880] bf16
  short* Wswz   = (short*)(ATb + (size_t)256*MTOT);    // [4][8][4][768][8] bf16 = 1.5 MB
  float* invmp  = (float*)(Wswz + (size_t)4*8*4*768*8);// 10880
  float* pooled = invmp + MTOT;                        // 40*256
  float* qt     = pooled + 40*RSn;                     // 8*6*768
  float* ctxsum = qt + Bn*6*QSn;                       // 8*768 (zeroed by k_front)
  int*   det    = (int*)(ctxsum + Bn*QSn);             // 2 ints (plain-written)
  int*   flags  = det + 4;                             // 40 ints
  float* hpre   = (float*)(flags + 40);                // 8*768

  k_front<<<815, 256, 0, stream>>>(cw[0], cw[1], cw[2], cw[3], Wswz,
                                   (const int*)mask[0], det, pl, hs, pooled, flags, ctxsum);
  k_mid<<<2096, 256, 0, stream>>>(feat[0], pos[0], mask[0],
                                  feat[1], pos[1], mask[1],
                                  feat[2], pos[2], mask[2],
                                  feat[3], pos[3], mask[3],
                                  det, ATb, invmp,
                                  lq, Wq, bq, qng, qnb, pooled, flags, qt);
  k_gemm_ln<<<340, 256, 0, stream>>>(ATb, Wswz, invmp,
                                     cb[0], cb[1], cb[2], cb[3],
                                     lg[0], lb[0], lg[1], lb[1],
                                     lg[2], lb[2], lg[3], lb[3], ctxsum);
  k_hpre<<<24, 256, 0, stream>>>(qt, ctxsum, W1, b1, hpre);
  k_out<<<13, 256, 0, stream>>>(hpre, W2, b2, out);
}

// Round 8
// 285.564 us; speedup vs baseline: 1.0918x; 1.0238x over previous
//
#include <hip/hip_runtime.h>
#include <hip/hip_bf16.h>

#define Bn 8
#define Qn 300
#define Pn 5
#define RSn 256
#define QSn 768
#define NCn 396
#define MTOT 10880
#define THRL -1.3862943611198906f   // log(0.2/0.8): sigmoid(x)>0.2 <=> x>THRL

typedef __attribute__((ext_vector_type(8))) short short8;
typedef __attribute__((ext_vector_type(4))) float float4v;

__device__ inline float wred(float v){
  #pragma unroll
  for (int off = 32; off; off >>= 1) v += __shfl_xor(v, off);
  return v;
}

__device__ __forceinline__ unsigned short f2bf(float f){
  union { float f; unsigned int u; } c; c.f = f;
  return (unsigned short)((c.u + 0x7FFF + ((c.u >> 16) & 1)) >> 16);   // RNE
}

// async global->LDS DMA, 16B per lane; LDS dest = uniform base + lane*16
__device__ __forceinline__ void gld_lds16(const short* g, short* l){
  __builtin_amdgcn_global_load_lds(
      (const __attribute__((address_space(1))) void*)g,
      (__attribute__((address_space(3))) void*)l, 16, 0, 0);
}

// mask weights for a 4-wide x 2-row window
__device__ __forceinline__ void mask_w(const void* M, int mbase, int mode, int i00, int H,
                                       float* w){
  if (mode == 0){
    int4 ma = *(const int4*)((const int*)M + mbase + i00);
    int4 mb = *(const int4*)((const int*)M + mbase + i00 + H);
    w[0]=ma.x?0.f:1.f; w[1]=ma.y?0.f:1.f; w[2]=ma.z?0.f:1.f; w[3]=ma.w?0.f:1.f;
    w[4]=mb.x?0.f:1.f; w[5]=mb.y?0.f:1.f; w[6]=mb.z?0.f:1.f; w[7]=mb.w?0.f:1.f;
  } else if (mode == 1){
    const unsigned char* Mb = (const unsigned char*)M + mbase;
    uchar4 ma = *(const uchar4*)(Mb + i00);
    uchar4 mb = *(const uchar4*)(Mb + i00 + H);
    w[0]=ma.x?0.f:1.f; w[1]=ma.y?0.f:1.f; w[2]=ma.z?0.f:1.f; w[3]=ma.w?0.f:1.f;
    w[4]=mb.x?0.f:1.f; w[5]=mb.y?0.f:1.f; w[6]=mb.z?0.f:1.f; w[7]=mb.w?0.f:1.f;
  } else {
    float4 ma = *(const float4*)((const float*)M + mbase + i00);
    float4 mb = *(const float4*)((const float*)M + mbase + i00 + H);
    w[0]=1.f-ma.x; w[1]=1.f-ma.y; w[2]=1.f-ma.z; w[3]=1.f-ma.w;
    w[4]=1.f-mb.x; w[5]=1.f-mb.y; w[6]=1.f-mb.z; w[7]=1.f-mb.w;
  }
}

// =====================================================================
// D1: k_front — [0,768): convW f32 -> bf16 swizzled Wswz[s][kc][lk][n][8]
//               768: mask detect ; [769,809): query pooling ;
//               [809,821): zero ctxsum+hpre ; [821,825): zero out
// =====================================================================
__global__ __launch_bounds__(256, 4) void k_front(
    const float* cw0, const float* cw1, const float* cw2, const float* cw3,
    short* Wswz, const int* __restrict__ m0, int* det,
    const float* __restrict__ pl, const float* __restrict__ hs,
    float* pooled, int* flags, float* ctxsum, float* outz){
  int bx = blockIdx.x;
  int t = threadIdx.x;
  if (bx < 768){
    int s = bx / 192;
    int linear = (bx % 192)*256 + t;
    int q = linear & 63, n = linear >> 6;
    const float* src = (s==0)?cw0:(s==1)?cw1:(s==2)?cw2:cw3;
    float4 f = *(const float4*)(src + (size_t)n*256 + q*4);
    int kc = q >> 3, lk = (q >> 1) & 3, e0 = (q & 1)*4;
    short* dst = Wswz + ((size_t)(s*8 + kc))*24576 + lk*6144 + n*8 + e0;
    short4 sv;
    sv.x = (short)f2bf(f.x); sv.y = (short)f2bf(f.y);
    sv.z = (short)f2bf(f.z); sv.w = (short)f2bf(f.w);
    *(short4*)dst = sv;
    return;
  }
  if (bx == 768){
    __shared__ int r0[4], r1[4];
    const int* mm = m0 + t*32;
    int d0 = 0, d1 = 0;
    #pragma unroll 8
    for (int i = 0; i < 32; ++i){
      int v = mm[i];
      d0 |= (v != 0 && v != 1);
      d1 |= (v != 0 && v != 0x3F800000);
    }
    unsigned long long bal0 = __ballot(d0), bal1 = __ballot(d1);
    int wid = t >> 6;
    if ((t & 63) == 0){ r0[wid] = (bal0 != 0ull); r1[wid] = (bal1 != 0ull); }
    __syncthreads();
    if (t == 0){
      det[0] = r0[0] | r0[1] | r0[2] | r0[3];
      det[1] = r1[0] | r1[1] | r1[2] | r1[3];
    }
    return;
  }
  if (bx >= 821){
    int idx = ((bx - 821)*256 + t)*4;
    if (idx < Bn*NCn) *(float4*)(outz + idx) = (float4){0.f,0.f,0.f,0.f};
    return;
  }
  if (bx >= 809){
    // zero ctxsum(6144) + hpre(6144) contiguous
    int idx = ((bx - 809)*256 + t)*4;
    *(float4*)(ctxsum + idx) = (float4){0.f,0.f,0.f,0.f};
    return;
  }
  // ---- query pooling (4-way unrolled, 4 independent chains)
  __shared__ float msk[Qn];
  int bb = (bx - 769) / Pn, p = (bx - 769) % Pn;
  for (int q = t; q < Qn; q += 256)
    msk[q] = (pl[(bb*Qn + q)*Pn + p] > THRL) ? 1.f : 0.f;
  __syncthreads();
  const float* hb = hs + (size_t)bb*Qn*RSn + t;
  float s0 = 0.f, s1 = 0.f, s2 = 0.f, s3 = 0.f, cnt = 0.f;
  for (int q = 0; q < Qn; q += 4){
    float m0v = msk[q], m1 = msk[q+1], m2 = msk[q+2], m3 = msk[q+3];
    cnt += m0v + m1 + m2 + m3;
    s0 = fmaf(m0v, hb[(size_t)(q  )*RSn], s0);
    s1 = fmaf(m1,  hb[(size_t)(q+1)*RSn], s1);
    s2 = fmaf(m2,  hb[(size_t)(q+2)*RSn], s2);
    s3 = fmaf(m3,  hb[(size_t)(q+3)*RSn], s3);
  }
  float ssum = (s0 + s1) + (s2 + s3);
  pooled[(bb*Pn + p)*RSn + t] = (cnt > 0.f) ? ssum / cnt : 0.f;
  if (t == 0) flags[bb*Pn + p] = (cnt > 0.f) ? 1 : 0;
}

// =====================================================================
// D2: k_mid — blocks [0,48): query tokens + LN -> qt
//   pool blocks p = bx-48:
//     s0: p<1024     : b=p>>7, c0=((p&127)>>1)*4, half=p&1 ; 4ch, 256 tokens
//     s1: [1024,1536): b=(p-1024)>>6, c0=((p-1024)&63)*4  ; 2ch/thread-half
//     s2: [1536,1792): b=(p-1536)>>5, c0=((p-1536)&31)*8  ; 1ch/thread
//     s3: [1792,1856): b=(p-1792)>>3, c0=((p-1792)&7)*32  ; 1ch/thread
// =====================================================================
__global__ __launch_bounds__(256, 4) void k_mid(
    const float* f0, const float* p0, const void* m0,
    const float* f1, const float* p1, const void* m1,
    const float* f2, const float* p2, const void* m2,
    const float* f3, const float* p3, const void* m3,
    const int* __restrict__ det, unsigned short* ATb, float* invmp,
    const float* __restrict__ lq, const float* __restrict__ Wq,
    const float* __restrict__ bq, const float* __restrict__ qng,
    const float* __restrict__ qnb, const float* __restrict__ pooled,
    const int* __restrict__ flags, float* qt){
  __shared__ float pq[256];
  __shared__ float s1s[4], s2s[4];
  int bx = blockIdx.x;
  int t = threadIdx.x;
  if (bx >= 48){
    int p = bx - 48;
    int mode = (det[0] == 0) ? 0 : ((det[1] == 0) ? 2 : 1);
    if (p < 1024){
      // ---- scale 0: H=64, T=1024. 4 channels, explicit load batching.
      int b = p >> 7, r = p & 127;
      int c0 = (r >> 1)*4, half = r & 1;
      const int H = 64, HH = 4096;
      int tk = half*256 + t;
      int ph = tk >> 4, pw = tk & 15;          // OW2 = 16
      int i00 = ph*128 + pw*4;
      int mbase = b*HH;
      float w[8];
      mask_w(m0, mbase, mode, i00, H, w);
      size_t plane = (size_t)(b*256 + c0)*HH + i00;
      const float* Fb = f0 + plane;
      const float* Pb = p0 + plane;
      float4 FA0 = *(const float4*)(Fb);
      float4 FB0 = *(const float4*)(Fb + H);
      float4 PA0 = *(const float4*)(Pb);
      float4 PB0 = *(const float4*)(Pb + H);
      float4 FA1 = *(const float4*)(Fb + HH);
      float4 FB1 = *(const float4*)(Fb + HH + H);
      float4 PA1 = *(const float4*)(Pb + HH);
      float4 PB1 = *(const float4*)(Pb + HH + H);
      float4 FA2 = *(const float4*)(Fb + 2*HH);
      float4 FB2 = *(const float4*)(Fb + 2*HH + H);
      float4 PA2 = *(const float4*)(Pb + 2*HH);
      float4 PB2 = *(const float4*)(Pb + 2*HH + H);
      float4 FA3 = *(const float4*)(Fb + 3*HH);
      float4 FB3 = *(const float4*)(Fb + 3*HH + H);
      float4 PA3 = *(const float4*)(Pb + 3*HH);
      float4 PB3 = *(const float4*)(Pb + 3*HH + H);
      float ms0 = w[0]+w[1]+w[4]+w[5];
      float ms1 = w[2]+w[3]+w[6]+w[7];
      float im0 = 1.f / fmaxf(ms0*0.25f, 1e-6f);
      float im1 = 1.f / fmaxf(ms1*0.25f, 1e-6f);
      float sc0 = 0.25f*im0, sc1 = 0.25f*im1;
      int mIdx = b*1024 + tk*2;
      #define DO_CH(cc, FA, FB, PA, PB) { \
        float x0 = (FA.x+PA.x)*w[0] + (FA.y+PA.y)*w[1] + (FB.x+PB.x)*w[4] + (FB.y+PB.y)*w[5]; \
        float x1 = (FA.z+PA.z)*w[2] + (FA.w+PA.w)*w[3] + (FB.z+PB.z)*w[6] + (FB.w+PB.w)*w[7]; \
        *(unsigned int*)(ATb + (size_t)(c0+cc)*MTOT + mIdx) = \
            (unsigned int)f2bf(x0*sc0) | ((unsigned int)f2bf(x1*sc1) << 16); }
      DO_CH(0, FA0, FB0, PA0, PB0)
      DO_CH(1, FA1, FB1, PA1, PB1)
      DO_CH(2, FA2, FB2, PA2, PB2)
      DO_CH(3, FA3, FB3, PA3, PB3)
      #undef DO_CH
      if (c0 == 0){ invmp[mIdx] = im0; invmp[mIdx+1] = im1; }
      return;
    }
    const float* F; const float* Pp; const void* M; int H, SB, T;
    int b, ch, tk; bool wr;
    if (p < 1536){
      int idx = p - 1024; b = idx >> 6;
      int c0 = (idx & 63)*4;
      F=f1; Pp=p1; M=m1; H=32; SB=8192; T=256;
      int ci = t >> 7; tk = t & 127;           // 2 channels per thread
      ch = c0 + ci*2; wr = (ch == 0);
      // handled below as 2-channel path
      int ph = tk >> 3, pw = tk & 7;           // OW2=8
      int i00 = ph*64 + pw*4;
      int HH = H*H, mbase = b*HH;
      float w[8]; mask_w(M, mbase, mode, i00, H, w);
      float ms0 = w[0]+w[1]+w[4]+w[5];
      float ms1 = w[2]+w[3]+w[6]+w[7];
      float im0 = 1.f / fmaxf(ms0*0.25f, 1e-6f);
      float im1 = 1.f / fmaxf(ms1*0.25f, 1e-6f);
      float sc0 = 0.25f*im0, sc1 = 0.25f*im1;
      int mIdx = SB + b*T + tk*2;
      size_t plane = (size_t)(b*256 + ch)*HH + i00;
      const float* Fb = F + plane; const float* Pb = Pp + plane;
      float4 FA0 = *(const float4*)(Fb);
      float4 FB0 = *(const float4*)(Fb + H);
      float4 PA0 = *(const float4*)(Pb);
      float4 PB0 = *(const float4*)(Pb + H);
      float4 FA1 = *(const float4*)(Fb + HH);
      float4 FB1 = *(const float4*)(Fb + HH + H);
      float4 PA1 = *(const float4*)(Pb + HH);
      float4 PB1 = *(const float4*)(Pb + HH + H);
      {
        float x0 = (FA0.x+PA0.x)*w[0] + (FA0.y+PA0.y)*w[1] + (FB0.x+PB0.x)*w[4] + (FB0.y+PB0.y)*w[5];
        float x1 = (FA0.z+PA0.z)*w[2] + (FA0.w+PA0.w)*w[3] + (FB0.z+PB0.z)*w[6] + (FB0.w+PB0.w)*w[7];
        *(unsigned int*)(ATb + (size_t)ch*MTOT + mIdx) =
            (unsigned int)f2bf(x0*sc0) | ((unsigned int)f2bf(x1*sc1) << 16);
        float y0 = (FA1.x+PA1.x)*w[0] + (FA1.y+PA1.y)*w[1] + (FB1.x+PB1.x)*w[4] + (FB1.y+PB1.y)*w[5];
        float y1 = (FA1.z+PA1.z)*w[2] + (FA1.w+PA1.w)*w[3] + (FB1.z+PB1.z)*w[6] + (FB1.w+PB1.w)*w[7];
        *(unsigned int*)(ATb + (size_t)(ch+1)*MTOT + mIdx) =
            (unsigned int)f2bf(y0*sc0) | ((unsigned int)f2bf(y1*sc1) << 16);
      }
      if (wr){ invmp[mIdx] = im0; invmp[mIdx+1] = im1; }
      return;
    }
    if (p < 1792){
      int idx = p - 1536; b = idx >> 5;
      ch = ((idx & 31)*8) + (t >> 5); tk = t & 31;
      F=f2; Pp=p2; M=m2; H=16; SB=10240; T=64;
    } else {
      int idx = p - 1792; b = idx >> 3;
      ch = ((idx & 7)*32) + (t >> 3); tk = t & 7;
      F=f3; Pp=p3; M=m3; H=8; SB=10752; T=16;
    }
    wr = (ch == 0);
    int OW2 = H >> 2;
    int ph = tk / OW2, pw = tk - ph*OW2;
    int i00 = ph*2*H + pw*4;
    int HH = H*H, mbase = b*HH;
    float w[8]; mask_w(M, mbase, mode, i00, H, w);
    float ms0 = w[0]+w[1]+w[4]+w[5];
    float ms1 = w[2]+w[3]+w[6]+w[7];
    float im0 = 1.f / fmaxf(ms0*0.25f, 1e-6f);
    float im1 = 1.f / fmaxf(ms1*0.25f, 1e-6f);
    float sc0 = 0.25f*im0, sc1 = 0.25f*im1;
    int mIdx = SB + b*T + tk*2;
    size_t plane = (size_t)(b*256 + ch)*HH + i00;
    const float* Fb = F + plane; const float* Pb = Pp + plane;
    float4 FA = *(const float4*)(Fb);
    float4 FB = *(const float4*)(Fb + H);
    float4 PA = *(const float4*)(Pb);
    float4 PB = *(const float4*)(Pb + H);
    float x0 = (FA.x+PA.x)*w[0] + (FA.y+PA.y)*w[1] + (FB.x+PB.x)*w[4] + (FB.y+PB.y)*w[5];
    float x1 = (FA.z+PA.z)*w[2] + (FA.w+PA.w)*w[3] + (FB.z+PB.z)*w[6] + (FB.w+PB.w)*w[7];
    *(unsigned int*)(ATb + (size_t)ch*MTOT + mIdx) =
        (unsigned int)f2bf(x0*sc0) | ((unsigned int)f2bf(x1*sc1) << 16);
    if (wr){ invmp[mIdx] = im0; invmp[mIdx+1] = im1; }
    return;
  }
  // ---- query tokens + LN (blocks 0..47)
  int b = bx / 6, j = bx % 6;
  float v0 = lq[j*QSn + t], v1 = lq[j*QSn + t + 256], v2 = lq[j*QSn + t + 512];
  int any = flags[b*Pn] | flags[b*Pn+1] | flags[b*Pn+2] | flags[b*Pn+3] | flags[b*Pn+4];
  if (j > 0 && any){
    pq[t] = pooled[(b*Pn + (j-1))*RSn + t];
    __syncthreads();
    float a0 = 0.f, a1 = 0.f, a2 = 0.f;
    #pragma unroll 8
    for (int c = 0; c < RSn; ++c){
      float pv = pq[c];
      a0 = fmaf(pv, Wq[c*QSn + t      ], a0);
      a1 = fmaf(pv, Wq[c*QSn + t + 256], a1);
      a2 = fmaf(pv, Wq[c*QSn + t + 512], a2);
    }
    v0 += a0 + bq[t]; v1 += a1 + bq[t+256]; v2 += a2 + bq[t+512];
  }
  float sm = v0 + v1 + v2, sq = v0*v0 + v1*v1 + v2*v2;
  sm = wred(sm); sq = wred(sq);
  int wid = t >> 6, lane = t & 63;
  if (lane == 0){ s1s[wid] = sm; s2s[wid] = sq; }
  __syncthreads();
  float S  = s1s[0] + s1s[1] + s1s[2] + s1s[3];
  float SQ = s2s[0] + s2s[1] + s2s[2] + s2s[3];
  float mu = S * (1.f/QSn), var = SQ * (1.f/QSn) - mu*mu;
  float rs = rsqrtf(var + 1e-5f);
  float* o = qt + (b*6 + j)*QSn;
  o[t      ] = (v0 - mu)*rs*qng[t      ] + qnb[t      ];
  o[t + 256] = (v1 - mu)*rs*qng[t + 256] + qnb[t + 256];
  o[t + 512] = (v2 - mu)*rs*qng[t + 512] + qnb[t + 512];
}

// =====================================================================
// D3: fused MFMA GEMM + bias + LayerNorm + token-sum.  340 blocks x 256 thr.
// (unchanged from R7 — isolating k_mid/tail deltas)
// =====================================================================
__global__ __launch_bounds__(256, 2) void k_gemm_ln(
    const unsigned short* __restrict__ ATb, const short* __restrict__ Wswz,
    const float* __restrict__ invmp,
    const float* cb0, const float* cb1, const float* cb2, const float* cb3,
    const float* lg0, const float* lb0, const float* lg1, const float* lb1,
    const float* lg2, const float* lb2, const float* lg3, const float* lb3,
    float* __restrict__ ctxsum){
  __shared__ short Bsh[24576];
  __shared__ float lsum[4][32], lsq[4][32];
  int m0 = blockIdx.x * 32;
  int s;
  if (m0 < 8192) s = 0;
  else if (m0 < 10240) s = 1;
  else if (m0 < 10752) s = 2;
  else s = 3;
  int b0, b1;
  if (s == 0){ b0 = m0 >> 10; b1 = b0; }
  else if (s == 1){ b0 = (m0 - 8192) >> 8; b1 = b0; }
  else if (s == 2){ b0 = (m0 - 10240) >> 6; b1 = b0; }
  else { b0 = (m0 - 10752) >> 4; b1 = b0 + 1; }
  const float *CB, *LG, *LB;
  if (s==0){ CB=cb0; LG=lg0; LB=lb0; }
  else if (s==1){ CB=cb1; LG=lg1; LB=lb1; }
  else if (s==2){ CB=cb2; LG=lg2; LB=lb2; }
  else { CB=cb3; LG=lg3; LB=lb3; }

  int t = threadIdx.x;
  int wid = t >> 6, l = t & 63;
  int lm = l & 15, lk = l >> 4;
  int nfb = wid * 12;

  {
    const unsigned short* src = ATb + (size_t)t*MTOT + m0;
    short8 a0 = *(const short8*)(src);
    short8 a1 = *(const short8*)(src + 8);
    short8 a2 = *(const short8*)(src + 16);
    short8 a3 = *(const short8*)(src + 24);
    #pragma unroll
    for (int e = 0; e < 8; ++e){
      Bsh[e*264 + t]      = a0[e];
      Bsh[(e+8)*264 + t]  = a1[e];
      Bsh[(e+16)*264 + t] = a2[e];
      Bsh[(e+24)*264 + t] = a3[e];
    }
  }
  __syncthreads();
  short8 aReg[2][8];
  #pragma unroll
  for (int mt = 0; mt < 2; ++mt)
    #pragma unroll
    for (int kc = 0; kc < 8; ++kc)
      aReg[mt][kc] = *(const short8*)(Bsh + (mt*16 + lm)*264 + kc*32 + lk*8);
  __syncthreads();

  float4v acc[2][12];
  #pragma unroll
  for (int mt = 0; mt < 2; ++mt)
    #pragma unroll
    for (int nf = 0; nf < 12; ++nf) acc[mt][nf] = (float4v){0.f,0.f,0.f,0.f};

  #pragma unroll
  for (int kc = 0; kc < 8; ++kc){
    const short* slice = Wswz + ((size_t)(s*8 + kc))*24576;
    #pragma unroll
    for (int j = 0; j < 12; ++j){
      int chunk = wid*12 + j;
      gld_lds16(slice + chunk*512 + l*8, Bsh + chunk*512);
    }
    __syncthreads();
    const short* bb = Bsh + lk*6144 + lm*8;
    #pragma unroll
    for (int nf = 0; nf < 12; ++nf){
      short8 bf = *(const short8*)(bb + (size_t)(nfb+nf)*128);
      acc[0][nf] = __builtin_amdgcn_mfma_f32_16x16x32_bf16(aReg[0][kc], bf, acc[0][nf], 0, 0, 0);
      acc[1][nf] = __builtin_amdgcn_mfma_f32_16x16x32_bf16(aReg[1][kc], bf, acc[1][nf], 0, 0, 0);
    }
    __syncthreads();
  }

  float im[2][4];
  #pragma unroll
  for (int mt = 0; mt < 2; ++mt)
    #pragma unroll
    for (int r = 0; r < 4; ++r) im[mt][r] = invmp[m0 + mt*16 + lk*4 + r];

  float sum[2][4] = {{0,0,0,0},{0,0,0,0}}, sq[2][4] = {{0,0,0,0},{0,0,0,0}};
  #pragma unroll
  for (int nf = 0; nf < 12; ++nf){
    float cbv = CB[(nfb+nf)*16 + lm];
    #pragma unroll
    for (int mt = 0; mt < 2; ++mt)
      #pragma unroll
      for (int r = 0; r < 4; ++r){
        float p = acc[mt][nf][r] + cbv*im[mt][r];
        acc[mt][nf][r] = p;
        sum[mt][r] += p;
        sq[mt][r] = fmaf(p, p, sq[mt][r]);
      }
  }
  #pragma unroll
  for (int mt = 0; mt < 2; ++mt)
    #pragma unroll
    for (int r = 0; r < 4; ++r){
      #pragma unroll
      for (int off = 1; off < 16; off <<= 1){
        sum[mt][r] += __shfl_xor(sum[mt][r], off);
        sq[mt][r]  += __shfl_xor(sq[mt][r],  off);
      }
    }
  if (lm == 0){
    #pragma unroll
    for (int mt = 0; mt < 2; ++mt)
      #pragma unroll
      for (int r = 0; r < 4; ++r){
        lsum[wid][mt*16 + lk*4 + r] = sum[mt][r];
        lsq[wid][mt*16 + lk*4 + r]  = sq[mt][r];
      }
  }
  __syncthreads();
  float mu[2][4], rs[2][4];
  #pragma unroll
  for (int mt = 0; mt < 2; ++mt)
    #pragma unroll
    for (int r = 0; r < 4; ++r){
      int row = mt*16 + lk*4 + r;
      float S  = lsum[0][row] + lsum[1][row] + lsum[2][row] + lsum[3][row];
      float SQ = lsq[0][row]  + lsq[1][row]  + lsq[2][row]  + lsq[3][row];
      mu[mt][r] = S * (1.f/768.f);
      float var = SQ * (1.f/768.f) - mu[mt][r]*mu[mt][r];
      rs[mt][r] = rsqrtf(var + 1e-5f);
    }
  #pragma unroll
  for (int nf = 0; nf < 12; ++nf){
    int n = (nfb+nf)*16 + lm;
    float g = LG[n], bb2 = LB[n];
    float tv0 = 0.f, tv1 = 0.f;
    #pragma unroll
    for (int r = 0; r < 4; ++r){
      tv0 += (acc[0][nf][r] - mu[0][r]) * rs[0][r];
      tv1 += (acc[1][nf][r] - mu[1][r]) * rs[1][r];
    }
    tv0 = tv0*g + 4.f*bb2;
    tv1 = tv1*g + 4.f*bb2;
    tv0 += __shfl_xor(tv0, 16); tv0 += __shfl_xor(tv0, 32);
    tv1 += __shfl_xor(tv1, 16); tv1 += __shfl_xor(tv1, 32);
    if (lk == 0){
      atomicAdd(&ctxsum[b0*768 + n], tv0);
      atomicAdd(&ctxsum[b1*768 + n], tv1);
    }
  }
}

// =====================================================================
// D4: k_hpre — hpre += v @ W1 (+b1). Grid 96 = 24n(32col) x 4k(192c).
// hpre pre-zeroed by k_front. Thread: 1 (b, o) pair, 192 fmaf.
// =====================================================================
__global__ void k_hpre(const float* __restrict__ qt, const float* __restrict__ ctxsum,
                       const float* __restrict__ W1, const float* __restrict__ b1,
                       float* __restrict__ hpre){
  __shared__ float vsh[Bn][192];
  int nc = blockIdx.x % 24, kc = blockIdx.x / 24;
  int n0 = nc*32, c0 = kc*192;
  int t = threadIdx.x;
  for (int i = t; i < Bn*192; i += 256){
    int b = i / 192, cl = i - b*192;
    int c = c0 + cl;
    const float* q = qt + (size_t)b*6*768;
    float pm = q[768+c] + q[2*768+c] + q[3*768+c] + q[4*768+c] + q[5*768+c];
    vsh[b][cl] = q[c] + 0.2f*pm + ctxsum[b*768 + c]*(1.f/680.f);
  }
  __syncthreads();
  int ow = t & 31, bi = t >> 5;
  int o = n0 + ow;
  float acc = 0.f;
  const float* w = W1 + (size_t)c0*768 + o;
  #pragma unroll 4
  for (int cl = 0; cl < 192; ++cl)
    acc = fmaf(vsh[bi][cl], w[(size_t)cl*768], acc);
  if (kc == 0) acc += b1[o];
  atomicAdd(&hpre[bi*768 + o], acc);
}

// =====================================================================
// D5: k_out — out += relu(hpre) @ W2 (+b2). Grid 52 = 13n(32) x 4k(192).
// out pre-zeroed by k_front.
// =====================================================================
__global__ void k_out(const float* __restrict__ hpre, const float* __restrict__ W2,
                      const float* __restrict__ b2, float* __restrict__ out){
  __shared__ float hsh[Bn][192];
  int nc = blockIdx.x % 13, kc = blockIdx.x / 13;
  int n0 = nc*32, c0 = kc*192;
  int t = threadIdx.x;
  for (int i = t; i < Bn*192; i += 256){
    int b = i / 192, cl = i - b*192;
    hsh[b][cl] = fmaxf(hpre[b*768 + c0 + cl], 0.f);
  }
  __syncthreads();
  int ow = t & 31, bi = t >> 5;
  int o = n0 + ow;
  if (o >= NCn) return;
  float acc = 0.f;
  const float* w = W2 + (size_t)c0*NCn + o;
  #pragma unroll 4
  for (int cl = 0; cl < 192; ++cl)
    acc = fmaf(hsh[bi][cl], w[(size_t)cl*NCn], acc);
  if (kc == 0) acc += b2[o];
  atomicAdd(&out[bi*NCn + o], acc);
}

extern "C" void kernel_launch(void* const* d_in, const int* in_sizes, int n_in,
                              void* d_out, int out_size, void* d_ws, size_t ws_size,
                              hipStream_t stream){
  const float* pl = (const float*)d_in[0];
  const float* hs = (const float*)d_in[2];
  const float* feat[4]; const float* pos[4]; const void* mask[4];
  const float* cw[4]; const float* cb[4]; const float* lg[4]; const float* lb[4];
  for (int s = 0; s < 4; ++s){
    int base = 3 + 7*s;
    feat[s] = (const float*)d_in[base];
    pos[s]  = (const float*)d_in[base+1];
    mask[s] = d_in[base+2];
    cw[s]   = (const float*)d_in[base+3];
    cb[s]   = (const float*)d_in[base+4];
    lg[s]   = (const float*)d_in[base+5];
    lb[s]   = (const float*)d_in[base+6];
  }
  const float* lq  = (const float*)d_in[31];
  const float* Wq  = (const float*)d_in[32];
  const float* bq  = (const float*)d_in[33];
  const float* qng = (const float*)d_in[34];
  const float* qnb = (const float*)d_in[35];
  const float* W1  = (const float*)d_in[36];
  const float* b1  = (const float*)d_in[37];
  const float* W2  = (const float*)d_in[38];
  const float* b2  = (const float*)d_in[39];
  float* out = (float*)d_out;

  // ---- workspace layout (~7.5 MB)
  unsigned short* ATb = (unsigned short*)d_ws;         // [256][10880] bf16
  short* Wswz   = (short*)(ATb + (size_t)256*MTOT);    // [4][8][4][768][8] bf16 = 1.5 MB
  float* invmp  = (float*)(Wswz + (size_t)4*8*4*768*8);// 10880
  float* pooled = invmp + MTOT;                        // 40*256
  float* qt     = pooled + 40*RSn;                     // 8*6*768
  float* ctxsum = qt + Bn*6*QSn;                       // 8*768 (zeroed by k_front)
  float* hpre   = ctxsum + Bn*QSn;                     // 8*768 (zeroed by k_front)
  int*   det    = (int*)(hpre + Bn*QSn);               // 2 ints
  int*   flags  = det + 4;                             // 40 ints

  k_front<<<825, 256, 0, stream>>>(cw[0], cw[1], cw[2], cw[3], Wswz,
                                   (const int*)mask[0], det, pl, hs, pooled, flags,
                                   ctxsum, out);
  k_mid<<<1904, 256, 0, stream>>>(feat[0], pos[0], mask[0],
                                  feat[1], pos[1], mask[1],
                                  feat[2], pos[2], mask[2],
                                  feat[3], pos[3], mask[3],
                                  det, ATb, invmp,
                                  lq, Wq, bq, qng, qnb, pooled, flags, qt);
  k_gemm_ln<<<340, 256, 0, stream>>>(ATb, Wswz, invmp,
                                     cb[0], cb[1], cb[2], cb[3],
                                     lg[0], lb[0], lg[1], lb[1],
                                     lg[2], lb[2], lg[3], lb[3], ctxsum);
  k_hpre<<<96, 256, 0, stream>>>(qt, ctxsum, W1, b1, hpre);
  k_out<<<52, 256, 0, stream>>>(hpre, W2, b2, out);
}

// Round 9
// 272.875 us; speedup vs baseline: 1.1425x; 1.0465x over previous
//
#include <hip/hip_runtime.h>
#include <hip/hip_bf16.h>

#define Bn 8
#define Qn 300
#define Pn 5
#define RSn 256
#define QSn 768
#define NCn 396
#define MTOT 10880
#define THRL -1.3862943611198906f   // log(0.2/0.8): sigmoid(x)>0.2 <=> x>THRL

typedef __attribute__((ext_vector_type(8))) short short8;
typedef __attribute__((ext_vector_type(4))) float float4v;

__device__ inline float wred(float v){
  #pragma unroll
  for (int off = 32; off; off >>= 1) v += __shfl_xor(v, off);
  return v;
}

__device__ __forceinline__ unsigned short f2bf(float f){
  union { float f; unsigned int u; } c; c.f = f;
  return (unsigned short)((c.u + 0x7FFF + ((c.u >> 16) & 1)) >> 16);   // RNE
}

// async global->LDS DMA, 16B per lane; LDS dest = uniform base + lane*16
__device__ __forceinline__ void gld_lds16(const short* g, short* l){
  __builtin_amdgcn_global_load_lds(
      (const __attribute__((address_space(1))) void*)g,
      (__attribute__((address_space(3))) void*)l, 16, 0, 0);
}

// =====================================================================
// D1: k_front — [0,768): convW f32 -> bf16 swizzled Wswz[s][kc][lk][n][8]
//               768: mask detect ; [769,809): query pooling ;
//               [809,821): zero ctxsum+hpre ; [821,825): zero out
// =====================================================================
__global__ __launch_bounds__(256, 4) void k_front(
    const float* cw0, const float* cw1, const float* cw2, const float* cw3,
    short* Wswz, const int* __restrict__ mk0, int* det,
    const float* __restrict__ pl, const float* __restrict__ hs,
    float* pooled, int* flags, float* ctxsum, float* outz){
  int bx = blockIdx.x;
  int t = threadIdx.x;
  if (bx < 768){
    int s = bx / 192;
    int linear = (bx % 192)*256 + t;
    int q = linear & 63, n = linear >> 6;
    const float* src = (s==0)?cw0:(s==1)?cw1:(s==2)?cw2:cw3;
    float4 f = *(const float4*)(src + (size_t)n*256 + q*4);
    int kc = q >> 3, lk = (q >> 1) & 3, e0 = (q & 1)*4;
    short* dst = Wswz + ((size_t)(s*8 + kc))*24576 + lk*6144 + n*8 + e0;
    short4 sv;
    sv.x = (short)f2bf(f.x); sv.y = (short)f2bf(f.y);
    sv.z = (short)f2bf(f.z); sv.w = (short)f2bf(f.w);
    *(short4*)dst = sv;
    return;
  }
  if (bx == 768){
    __shared__ int r0[4], r1[4];
    const int* mm = mk0 + t*32;
    int d0 = 0, d1 = 0;
    #pragma unroll 8
    for (int i = 0; i < 32; ++i){
      int v = mm[i];
      d0 |= (v != 0 && v != 1);
      d1 |= (v != 0 && v != 0x3F800000);
    }
    unsigned long long bal0 = __ballot(d0), bal1 = __ballot(d1);
    int wid = t >> 6;
    if ((t & 63) == 0){ r0[wid] = (bal0 != 0ull); r1[wid] = (bal1 != 0ull); }
    __syncthreads();
    if (t == 0){
      det[0] = r0[0] | r0[1] | r0[2] | r0[3];
      det[1] = r1[0] | r1[1] | r1[2] | r1[3];
    }
    return;
  }
  if (bx >= 821){
    int idx = ((bx - 821)*256 + t)*4;
    if (idx < Bn*NCn) *(float4*)(outz + idx) = (float4){0.f,0.f,0.f,0.f};
    return;
  }
  if (bx >= 809){
    int idx = ((bx - 809)*256 + t)*4;      // zero ctxsum(6144)+hpre(6144)
    *(float4*)(ctxsum + idx) = (float4){0.f,0.f,0.f,0.f};
    return;
  }
  // ---- query pooling (4-way unrolled independent chains)
  __shared__ float msk[Qn];
  int bb = (bx - 769) / Pn, p = (bx - 769) % Pn;
  for (int q = t; q < Qn; q += 256)
    msk[q] = (pl[(bb*Qn + q)*Pn + p] > THRL) ? 1.f : 0.f;
  __syncthreads();
  const float* hb = hs + (size_t)bb*Qn*RSn + t;
  float s0 = 0.f, s1 = 0.f, s2 = 0.f, s3 = 0.f, cnt = 0.f;
  for (int q = 0; q < Qn; q += 4){
    float m0v = msk[q], m1 = msk[q+1], m2 = msk[q+2], m3 = msk[q+3];
    cnt += m0v + m1 + m2 + m3;
    s0 = fmaf(m0v, hb[(size_t)(q  )*RSn], s0);
    s1 = fmaf(m1,  hb[(size_t)(q+1)*RSn], s1);
    s2 = fmaf(m2,  hb[(size_t)(q+2)*RSn], s2);
    s3 = fmaf(m3,  hb[(size_t)(q+3)*RSn], s3);
  }
  float ssum = (s0 + s1) + (s2 + s3);
  pooled[(bb*Pn + p)*RSn + t] = (cnt > 0.f) ? ssum / cnt : 0.f;
  if (t == 0) flags[bb*Pn + p] = (cnt > 0.f) ? 1 : 0;
}

// =====================================================================
// D2: k_pgemm — blocks [0,340): fused pool + MFMA GEMM + bias + LN + token-sum
//               blocks [340,388): query tokens + LN -> qt
// Pool phase: block's 32 tokens x 256 ch pooled straight into LDS As[m][k]
// (each pixel belongs to exactly one token -> zero duplicated traffic).
// GEMM phase: B staged per-kc via global_load_lds DMA of pre-swizzled Wswz.
// =====================================================================
__global__ __launch_bounds__(256, 2) void k_pgemm(
    const float* fe0, const float* po0, const void* ma0,
    const float* fe1, const float* po1, const void* ma1,
    const float* fe2, const float* po2, const void* ma2,
    const float* fe3, const float* po3, const void* ma3,
    const int* __restrict__ det, const short* __restrict__ Wswz,
    const float* cb0, const float* cb1, const float* cb2, const float* cb3,
    const float* lg0, const float* lb0, const float* lg1, const float* lb1,
    const float* lg2, const float* lb2, const float* lg3, const float* lb3,
    float* __restrict__ ctxsum,
    const float* __restrict__ lq, const float* __restrict__ Wq,
    const float* __restrict__ bq, const float* __restrict__ qng,
    const float* __restrict__ qnb, const float* __restrict__ pooled,
    const int* __restrict__ flags, float* qt){
  __shared__ short Bsh[24576];        // 48 KB B-tile
  __shared__ short As[32*264];        // 16.5 KB A-tile [m][k], pitch 264
  __shared__ float wls[32][4];
  __shared__ float scls[32], imls[32];
  __shared__ float lsum[4][32], lsq[4][32];
  __shared__ float pq[256];
  __shared__ float s1s[4], s2s[4];
  int blk = blockIdx.x;
  int t = threadIdx.x;

  if (blk >= 340){
    // ---- query tokens + LN
    int qbx = blk - 340;
    int b = qbx / 6, j = qbx % 6;
    float v0 = lq[j*QSn + t], v1 = lq[j*QSn + t + 256], v2 = lq[j*QSn + t + 512];
    int any = flags[b*Pn] | flags[b*Pn+1] | flags[b*Pn+2] | flags[b*Pn+3] | flags[b*Pn+4];
    if (j > 0 && any){
      pq[t] = pooled[(b*Pn + (j-1))*RSn + t];
      __syncthreads();
      float a0 = 0.f, a1 = 0.f, a2 = 0.f;
      #pragma unroll 8
      for (int c = 0; c < RSn; ++c){
        float pv = pq[c];
        a0 = fmaf(pv, Wq[c*QSn + t      ], a0);
        a1 = fmaf(pv, Wq[c*QSn + t + 256], a1);
        a2 = fmaf(pv, Wq[c*QSn + t + 512], a2);
      }
      v0 += a0 + bq[t]; v1 += a1 + bq[t+256]; v2 += a2 + bq[t+512];
    }
    float sm = v0 + v1 + v2, sq = v0*v0 + v1*v1 + v2*v2;
    sm = wred(sm); sq = wred(sq);
    int wid = t >> 6, lane = t & 63;
    if (lane == 0){ s1s[wid] = sm; s2s[wid] = sq; }
    __syncthreads();
    float S  = s1s[0] + s1s[1] + s1s[2] + s1s[3];
    float SQ = s2s[0] + s2s[1] + s2s[2] + s2s[3];
    float mu = S * (1.f/QSn), var = SQ * (1.f/QSn) - mu*mu;
    float rs = rsqrtf(var + 1e-5f);
    float* o = qt + (b*6 + j)*QSn;
    o[t      ] = (v0 - mu)*rs*qng[t      ] + qnb[t      ];
    o[t + 256] = (v1 - mu)*rs*qng[t + 256] + qnb[t + 256];
    o[t + 512] = (v2 - mu)*rs*qng[t + 512] + qnb[t + 512];
    return;
  }

  int m0 = blk * 32;
  int s, H, OWlog, b0, b1;
  const float *F, *Pp; const void* M;
  const float *CB, *LG, *LB;
  if (m0 < 8192){ s=0; F=fe0; Pp=po0; M=ma0; H=64; OWlog=5; b0=m0>>10; b1=b0;
                  CB=cb0; LG=lg0; LB=lb0; }
  else if (m0 < 10240){ s=1; F=fe1; Pp=po1; M=ma1; H=32; OWlog=4; b0=(m0-8192)>>8; b1=b0;
                  CB=cb1; LG=lg1; LB=lb1; }
  else if (m0 < 10752){ s=2; F=fe2; Pp=po2; M=ma2; H=16; OWlog=3; b0=(m0-10240)>>6; b1=b0;
                  CB=cb2; LG=lg2; LB=lb2; }
  else { s=3; F=fe3; Pp=po3; M=ma3; H=8; OWlog=2; b0=(m0-10752)>>4; b1=b0+1;
                  CB=cb3; LG=lg3; LB=lb3; }
  int HH = H*H;
  int OWm = (H >> 1) - 1;
  int mode = (det[0] == 0) ? 0 : ((det[1] == 0) ? 2 : 1);

  // per-slot token geometry (slot = t&31; also step-1 tokens for t<32)
  int slot = t & 31;
  int gm = m0 + slot;
  int bb, ltl;
  if (s == 0){ bb = gm >> 10; ltl = gm & 1023; }
  else if (s == 1){ bb = (gm - 8192) >> 8; ltl = gm & 255; }
  else if (s == 2){ bb = (gm - 10240) >> 6; ltl = gm & 63; }
  else { bb = (gm - 10752) >> 4; ltl = gm & 15; }
  int ph = ltl >> OWlog, pw = ltl & OWm;
  int i00 = ph*2*H + pw*2;
  int mbase = bb*HH;

  // ---- step 1: mask weights per token (threads 0..31)
  if (t < 32){
    float w0, w1, w2, w3;
    if (mode == 0){
      const int* Mi = (const int*)M + mbase + i00;
      int2 ma = *(const int2*)(Mi);
      int2 mb = *(const int2*)(Mi + H);
      w0 = ma.x?0.f:1.f; w1 = ma.y?0.f:1.f; w2 = mb.x?0.f:1.f; w3 = mb.y?0.f:1.f;
    } else if (mode == 1){
      const unsigned char* Mb = (const unsigned char*)M + mbase + i00;
      w0 = Mb[0]?0.f:1.f; w1 = Mb[1]?0.f:1.f; w2 = Mb[H]?0.f:1.f; w3 = Mb[H+1]?0.f:1.f;
    } else {
      const float* Mf = (const float*)M + mbase + i00;
      float2 ma = *(const float2*)(Mf);
      float2 mb = *(const float2*)(Mf + H);
      w0 = 1.f-ma.x; w1 = 1.f-ma.y; w2 = 1.f-mb.x; w3 = 1.f-mb.y;
    }
    float msum = w0 + w1 + w2 + w3;
    float im = 1.f / fmaxf(msum*0.25f, 1e-6f);
    wls[t][0] = w0; wls[t][1] = w1; wls[t][2] = w2; wls[t][3] = w3;
    scls[t] = 0.25f*im; imls[t] = im;
  }
  __syncthreads();

  // ---- step 2: pool 256 channels into As[m][k]; 2 ch/thread/round, 16 rounds
  {
    float w0 = wls[slot][0], w1 = wls[slot][1], w2 = wls[slot][2], w3 = wls[slot][3];
    float sc = scls[slot];
    int chb = (t >> 5) * 2;
    size_t base = (size_t)(bb*256 + chb)*HH + i00;
    const float* Fp = F + base;
    const float* Pq = Pp + base;
    const int stride = 16*HH;
    #pragma unroll 2
    for (int r = 0; r < 16; ++r){
      float2 fa0 = *(const float2*)(Fp);
      float2 fb0 = *(const float2*)(Fp + H);
      float2 pa0 = *(const float2*)(Pq);
      float2 pb0 = *(const float2*)(Pq + H);
      float2 fa1 = *(const float2*)(Fp + HH);
      float2 fb1 = *(const float2*)(Fp + HH + H);
      float2 pa1 = *(const float2*)(Pq + HH);
      float2 pb1 = *(const float2*)(Pq + HH + H);
      float x0 = (fa0.x+pa0.x)*w0 + (fa0.y+pa0.y)*w1 + (fb0.x+pb0.x)*w2 + (fb0.y+pb0.y)*w3;
      float x1 = (fa1.x+pa1.x)*w0 + (fa1.y+pa1.y)*w1 + (fb1.x+pb1.x)*w2 + (fb1.y+pb1.y)*w3;
      *(unsigned int*)(&As[slot*264 + chb + r*16]) =
          (unsigned int)f2bf(x0*sc) | ((unsigned int)f2bf(x1*sc) << 16);
      Fp += stride; Pq += stride;
    }
  }
  __syncthreads();

  // ---- A fragments to registers
  int wid = t >> 6, l = t & 63;
  int lm = l & 15, lk = l >> 4;
  int nfb = wid * 12;
  short8 aReg[2][8];
  #pragma unroll
  for (int mt = 0; mt < 2; ++mt)
    #pragma unroll
    for (int kc = 0; kc < 8; ++kc)
      aReg[mt][kc] = *(const short8*)(As + (mt*16 + lm)*264 + kc*32 + lk*8);

  float4v acc[2][12];
  #pragma unroll
  for (int mt = 0; mt < 2; ++mt)
    #pragma unroll
    for (int nf = 0; nf < 12; ++nf) acc[mt][nf] = (float4v){0.f,0.f,0.f,0.f};

  // ---- K loop: B via DMA, MFMA
  #pragma unroll
  for (int kc = 0; kc < 8; ++kc){
    const short* slice = Wswz + ((size_t)(s*8 + kc))*24576;
    #pragma unroll
    for (int j = 0; j < 12; ++j){
      int chunk = wid*12 + j;
      gld_lds16(slice + chunk*512 + l*8, Bsh + chunk*512);
    }
    __syncthreads();
    const short* bb2 = Bsh + lk*6144 + lm*8;
    #pragma unroll
    for (int nf = 0; nf < 12; ++nf){
      short8 bf = *(const short8*)(bb2 + (size_t)(nfb+nf)*128);
      acc[0][nf] = __builtin_amdgcn_mfma_f32_16x16x32_bf16(aReg[0][kc], bf, acc[0][nf], 0, 0, 0);
      acc[1][nf] = __builtin_amdgcn_mfma_f32_16x16x32_bf16(aReg[1][kc], bf, acc[1][nf], 0, 0, 0);
    }
    __syncthreads();
  }

  // ---- epilogue: bias (via LDS im), per-row LN, token-sum -> ctxsum
  float im[2][4];
  #pragma unroll
  for (int mt = 0; mt < 2; ++mt)
    #pragma unroll
    for (int r = 0; r < 4; ++r) im[mt][r] = imls[mt*16 + lk*4 + r];

  float sum[2][4] = {{0,0,0,0},{0,0,0,0}}, sq[2][4] = {{0,0,0,0},{0,0,0,0}};
  #pragma unroll
  for (int nf = 0; nf < 12; ++nf){
    float cbv = CB[(nfb+nf)*16 + lm];
    #pragma unroll
    for (int mt = 0; mt < 2; ++mt)
      #pragma unroll
      for (int r = 0; r < 4; ++r){
        float p = acc[mt][nf][r] + cbv*im[mt][r];
        acc[mt][nf][r] = p;
        sum[mt][r] += p;
        sq[mt][r] = fmaf(p, p, sq[mt][r]);
      }
  }
  #pragma unroll
  for (int mt = 0; mt < 2; ++mt)
    #pragma unroll
    for (int r = 0; r < 4; ++r){
      #pragma unroll
      for (int off = 1; off < 16; off <<= 1){
        sum[mt][r] += __shfl_xor(sum[mt][r], off);
        sq[mt][r]  += __shfl_xor(sq[mt][r],  off);
      }
    }
  if (lm == 0){
    #pragma unroll
    for (int mt = 0; mt < 2; ++mt)
      #pragma unroll
      for (int r = 0; r < 4; ++r){
        lsum[wid][mt*16 + lk*4 + r] = sum[mt][r];
        lsq[wid][mt*16 + lk*4 + r]  = sq[mt][r];
      }
  }
  __syncthreads();
  float mu[2][4], rs[2][4];
  #pragma unroll
  for (int mt = 0; mt < 2; ++mt)
    #pragma unroll
    for (int r = 0; r < 4; ++r){
      int row = mt*16 + lk*4 + r;
      float S  = lsum[0][row] + lsum[1][row] + lsum[2][row] + lsum[3][row];
      float SQ = lsq[0][row]  + lsq[1][row]  + lsq[2][row]  + lsq[3][row];
      mu[mt][r] = S * (1.f/768.f);
      float var = SQ * (1.f/768.f) - mu[mt][r]*mu[mt][r];
      rs[mt][r] = rsqrtf(var + 1e-5f);
    }
  #pragma unroll
  for (int nf = 0; nf < 12; ++nf){
    int n = (nfb+nf)*16 + lm;
    float g = LG[n], bv = LB[n];
    float tv0 = 0.f, tv1 = 0.f;
    #pragma unroll
    for (int r = 0; r < 4; ++r){
      tv0 += (acc[0][nf][r] - mu[0][r]) * rs[0][r];
      tv1 += (acc[1][nf][r] - mu[1][r]) * rs[1][r];
    }
    tv0 = tv0*g + 4.f*bv;
    tv1 = tv1*g + 4.f*bv;
    tv0 += __shfl_xor(tv0, 16); tv0 += __shfl_xor(tv0, 32);
    tv1 += __shfl_xor(tv1, 16); tv1 += __shfl_xor(tv1, 32);
    if (lk == 0){
      atomicAdd(&ctxsum[b0*768 + n], tv0);
      atomicAdd(&ctxsum[b1*768 + n], tv1);
    }
  }
}

// =====================================================================
// D3: k_hpre — hpre += v @ W1 (+b1). Grid 96 = 24n(32col) x 4k(192c).
// =====================================================================
__global__ void k_hpre(const float* __restrict__ qt, const float* __restrict__ ctxsum,
                       const float* __restrict__ W1, const float* __restrict__ b1,
                       float* __restrict__ hpre){
  __shared__ float vsh[Bn][192];
  int nc = blockIdx.x % 24, kc = blockIdx.x / 24;
  int n0 = nc*32, c0 = kc*192;
  int t = threadIdx.x;
  for (int i = t; i < Bn*192; i += 256){
    int b = i / 192, cl = i - b*192;
    int c = c0 + cl;
    const float* q = qt + (size_t)b*6*768;
    float pm = q[768+c] + q[2*768+c] + q[3*768+c] + q[4*768+c] + q[5*768+c];
    vsh[b][cl] = q[c] + 0.2f*pm + ctxsum[b*768 + c]*(1.f/680.f);
  }
  __syncthreads();
  int ow = t & 31, bi = t >> 5;
  int o = n0 + ow;
  float acc = 0.f;
  const float* w = W1 + (size_t)c0*768 + o;
  #pragma unroll 4
  for (int cl = 0; cl < 192; ++cl)
    acc = fmaf(vsh[bi][cl], w[(size_t)cl*768], acc);
  if (kc == 0) acc += b1[o];
  atomicAdd(&hpre[bi*768 + o], acc);
}

// =====================================================================
// D4: k_out — out += relu(hpre) @ W2 (+b2). Grid 52 = 13n(32) x 4k(192).
// =====================================================================
__global__ void k_out(const float* __restrict__ hpre, const float* __restrict__ W2,
                      const float* __restrict__ b2, float* __restrict__ out){
  __shared__ float hsh[Bn][192];
  int nc = blockIdx.x % 13, kc = blockIdx.x / 13;
  int n0 = nc*32, c0 = kc*192;
  int t = threadIdx.x;
  for (int i = t; i < Bn*192; i += 256){
    int b = i / 192, cl = i - b*192;
    hsh[b][cl] = fmaxf(hpre[b*768 + c0 + cl], 0.f);
  }
  __syncthreads();
  int ow = t & 31, bi = t >> 5;
  int o = n0 + ow;
  if (o >= NCn) return;
  float acc = 0.f;
  const float* w = W2 + (size_t)c0*NCn + o;
  #pragma unroll 4
  for (int cl = 0; cl < 192; ++cl)
    acc = fmaf(hsh[bi][cl], w[(size_t)cl*NCn], acc);
  if (kc == 0) acc += b2[o];
  atomicAdd(&out[bi*NCn + o], acc);
}

extern "C" void kernel_launch(void* const* d_in, const int* in_sizes, int n_in,
                              void* d_out, int out_size, void* d_ws, size_t ws_size,
                              hipStream_t stream){
  const float* pl = (const float*)d_in[0];
  const float* hs = (const float*)d_in[2];
  const float* feat[4]; const float* pos[4]; const void* mask[4];
  const float* cw[4]; const float* cb[4]; const float* lg[4]; const float* lb[4];
  for (int s = 0; s < 4; ++s){
    int base = 3 + 7*s;
    feat[s] = (const float*)d_in[base];
    pos[s]  = (const float*)d_in[base+1];
    mask[s] = d_in[base+2];
    cw[s]   = (const float*)d_in[base+3];
    cb[s]   = (const float*)d_in[base+4];
    lg[s]   = (const float*)d_in[base+5];
    lb[s]   = (const float*)d_in[base+6];
  }
  const float* lq  = (const float*)d_in[31];
  const float* Wq  = (const float*)d_in[32];
  const float* bq  = (const float*)d_in[33];
  const float* qng = (const float*)d_in[34];
  const float* qnb = (const float*)d_in[35];
  const float* W1  = (const float*)d_in[36];
  const float* b1  = (const float*)d_in[37];
  const float* W2  = (const float*)d_in[38];
  const float* b2  = (const float*)d_in[39];
  float* out = (float*)d_out;

  // ---- workspace layout (~1.7 MB)
  short* Wswz   = (short*)d_ws;                        // [4][8][4][768][8] bf16 = 1.5 MB
  float* pooled = (float*)(Wswz + (size_t)4*8*4*768*8);// 40*256
  float* qt     = pooled + 40*RSn;                     // 8*6*768
  float* ctxsum = qt + Bn*6*QSn;                       // 8*768 (zeroed by k_front)
  float* hpre   = ctxsum + Bn*QSn;                     // 8*768 (zeroed by k_front)
  int*   det    = (int*)(hpre + Bn*QSn);               // 2 ints
  int*   flags  = det + 4;                             // 40 ints

  k_front<<<825, 256, 0, stream>>>(cw[0], cw[1], cw[2], cw[3], Wswz,
                                   (const int*)mask[0], det, pl, hs, pooled, flags,
                                   ctxsum, out);
  k_pgemm<<<388, 256, 0, stream>>>(feat[0], pos[0], mask[0],
                                   feat[1], pos[1], mask[1],
                                   feat[2], pos[2], mask[2],
                                   feat[3], pos[3], mask[3],
                                   det, Wswz,
                                   cb[0], cb[1], cb[2], cb[3],
                                   lg[0], lb[0], lg[1], lb[1],
                                   lg[2], lb[2], lg[3], lb[3], ctxsum,
                                   lq, Wq, bq, qng, qnb, pooled, flags, qt);
  k_hpre<<<96, 256, 0, stream>>>(qt, ctxsum, W1, b1, hpre);
  k_out<<<52, 256, 0, stream>>>(hpre, W2, b2, out);
}